// Round 4
// baseline (1622.412 us; speedup 1.0000x reference)
//
#include <hip/hip_runtime.h>

#define Bz 8
#define Nn 2048
#define Cc 128
#define KK 16
#define WD 512
#define F2 64
#define FO 128
#define NP (Bz*Nn)
#define SQ2 1.41421356237309515f
#define HSTRIDE 136   // padded bf16 row stride (16B-aligned, conflict-friendly)
#define CAPMAX 256

// ws layout (float offsets)
#define GOFF   ((size_t)0)
#define BEOFF  ((size_t)1024)
#define LSOFF  ((size_t)2048)
#define HOFF   ((size_t)3072)
#define SQOFF  (HOFF + (size_t)NP*Cc)
#define A1OFF  (SQOFF + (size_t)NP)
#define ADOFF  (A1OFF + (size_t)NP*F2)
#define HXOFF  (ADOFF + (size_t)NP*Cc)
#define IXOFF  (HXOFF + (size_t)NP*Cc)
#define CNTOFF (IXOFF + (size_t)NP*KK)
// byte offsets for the u16 arrays
#define HIBYTES   ((CNTOFF + (size_t)NP) * 4)
#define CANDBYTES (HIBYTES + (size_t)NP*HSTRIDE*2)

typedef __attribute__((ext_vector_type(8))) short bf16x8;
typedef __attribute__((ext_vector_type(4))) float f32x4;

__device__ __forceinline__ unsigned short f2bf(float f) {
  unsigned u = __float_as_uint(f);
  unsigned r = (u + 0x7FFFu + ((u >> 16) & 1u)) >> 16;
  return (unsigned short)r;
}

// ---------------------------------------------------------------------------
// Kernel 1: per-batch FiLM vectors
__global__ __launch_bounds__(512) void k_pervec(const float* __restrict__ w,
    const float* __restrict__ Wg, const float* __restrict__ Wb,
    const float* __restrict__ Wls, const float* __restrict__ bls,
    float* __restrict__ ws) {
  __shared__ float red[3][4][Cc];
  const int b = blockIdx.x;
  const int c = threadIdx.x & 127, dc = threadIdx.x >> 7;
  const float* wr = w + b*WD;
  float ag = 0.f, ab = 0.f, al = 0.f;
  for (int d = dc*128; d < dc*128 + 128; ++d) {
    float wv = wr[d];
    ag = fmaf(wv, Wg[d*Cc + c], ag);
    ab = fmaf(wv, Wb[d*Cc + c], ab);
    al = fmaf(wv, Wls[d*Cc + c], al);
  }
  red[0][dc][c] = ag; red[1][dc][c] = ab; red[2][dc][c] = al;
  __syncthreads();
  if (dc == 0) {
    float sg = red[0][0][c] + red[0][1][c] + red[0][2][c] + red[0][3][c];
    float sb = red[1][0][c] + red[1][1][c] + red[1][2][c] + red[1][3][c];
    float sl = red[2][0][c] + red[2][1][c] + red[2][2][c] + red[2][3][c];
    ws[GOFF  + b*Cc + c] = 1.0f + sg;
    ws[BEOFF + b*Cc + c] = sb;
    ws[LSOFF + b*Cc + c] = sl + bls[c];
  }
}

// ---------------------------------------------------------------------------
// Kernel 2: h = LN(x)*g + beta, sq = sum(h*h), hi = bf16(h) (padded rows)
__global__ __launch_bounds__(64) void k_h(const float* __restrict__ x,
                                          float* __restrict__ ws,
                                          unsigned short* __restrict__ hi_g) {
  const int n = blockIdx.x;
  const int b = n >> 11;
  const int t = threadIdx.x;
  const float* xr = x + (size_t)n*Cc;
  float x0 = xr[t], x1 = xr[t + 64];
  float s = x0 + x1, ss = x0*x0 + x1*x1;
  #pragma unroll
  for (int m = 1; m < 64; m <<= 1) {
    s  += __shfl_xor(s,  m, 64);
    ss += __shfl_xor(ss, m, 64);
  }
  float mu  = s * (1.0f/128.0f);
  float var = ss * (1.0f/128.0f) - mu*mu;
  float rs  = rsqrtf(var + 1e-5f);
  float h0 = (x0 - mu)*rs*ws[GOFF + b*Cc + t]      + ws[BEOFF + b*Cc + t];
  float h1 = (x1 - mu)*rs*ws[GOFF + b*Cc + t + 64] + ws[BEOFF + b*Cc + t + 64];
  float* hr = ws + HOFF + (size_t)n*Cc;
  hr[t] = h0; hr[t + 64] = h1;
  hi_g[(size_t)n*HSTRIDE + t]      = f2bf(h0);
  hi_g[(size_t)n*HSTRIDE + t + 64] = f2bf(h1);
  float q = h0*h0 + h1*h1;
  #pragma unroll
  for (int m = 1; m < 64; m <<= 1) q += __shfl_xor(q, m, 64);
  if (t == 0) ws[SQOFF + n] = q;
}

// ---------------------------------------------------------------------------
// Kernel 3: precompute A1 = h@W1, Ad = h@Wx1[128:], hxb = h@Wx1[:128]-Ad+bx1
__global__ __launch_bounds__(128) void k_pre(const float* __restrict__ W1,
    const float* __restrict__ Wx1, const float* __restrict__ bx1,
    float* __restrict__ ws) {
  __shared__ float hs[4][Cc];
  const int t = threadIdx.x;
  const size_t row0 = (size_t)blockIdx.x * 4;
  const float* h = ws + HOFF;
  #pragma unroll
  for (int r = 0; r < 4; ++r) hs[r][t] = h[(row0 + r)*Cc + t];
  __syncthreads();
  float ad[4] = {0,0,0,0}, ac[4] = {0,0,0,0};
  for (int cp = 0; cp < Cc; ++cp) {
    float whi = Wx1[cp*FO + t];
    float wlo = Wx1[(Cc + cp)*FO + t];
    #pragma unroll
    for (int r = 0; r < 4; ++r) {
      float hv = hs[r][cp];
      ac[r] = fmaf(hv, whi, ac[r]);
      ad[r] = fmaf(hv, wlo, ad[r]);
    }
  }
  float bx = bx1[t];
  #pragma unroll
  for (int r = 0; r < 4; ++r) {
    ws[ADOFF + (row0 + r)*Cc + t] = ad[r];
    ws[HXOFF + (row0 + r)*Cc + t] = ac[r] - ad[r] + bx;
  }
  const int j = t & 63, rp = t >> 6;
  float a0 = 0.f, a1 = 0.f;
  for (int cp = 0; cp < Cc; ++cp) {
    float wv = W1[cp*F2 + j];
    a0 = fmaf(hs[rp][cp],     wv, a0);
    a1 = fmaf(hs[rp + 2][cp], wv, a1);
  }
  ws[A1OFF + (row0 + rp)*F2 + j]     = a0;
  ws[A1OFF + (row0 + rp + 2)*F2 + j] = a1;
}

// ---------------------------------------------------------------------------
// Kernel 4: MFMA approx distances + tau-filter compaction. (unchanged from r3)
__global__ __launch_bounds__(512, 1) void k_filter(float* __restrict__ ws,
    const unsigned short* __restrict__ hi_g, unsigned short* __restrict__ cand,
    int* __restrict__ cnt_g, int CAP) {
  __shared__ unsigned short hiA[64*HSTRIDE];   // 17408 B
  __shared__ float smB[8704];                  // hB u16[128*136] / dstage f32[64*132]
  __shared__ float sqA[64], sqB[128], tauS[64];
  __shared__ int cnt[64];
  unsigned short* hB = (unsigned short*)smB;
  float* dstage = smB;                         // stride 132
  const int t = threadIdx.x;
  const int b = blockIdx.x >> 5;
  const int i0 = (blockIdx.x & 31) << 6;
  const int wave = t >> 6, lane = t & 63;
  const int wi = wave & 1, wj = wave >> 1;     // wj 0..3
  const int l15 = lane & 15, l4 = lane >> 4;
  const float* __restrict__ sq = ws + SQOFF + (size_t)b*Nn;
  const unsigned short* __restrict__ hib = hi_g + (size_t)b*Nn*HSTRIDE;

  { // load hiA: 64 rows x 128 cols (pad never read)
    int r = t >> 3, o = (t & 7) * 16;
    *(bf16x8*)&hiA[r*HSTRIDE + o]     = *(const bf16x8*)&hib[(size_t)(i0 + r)*HSTRIDE + o];
    *(bf16x8*)&hiA[r*HSTRIDE + o + 8] = *(const bf16x8*)&hib[(size_t)(i0 + r)*HSTRIDE + o + 8];
  }
  if (t < 64) { sqA[t] = sq[i0 + t]; cnt[t] = 0; }

  for (int jt = 0; jt < 16; ++jt) {
    const int j0 = jt << 7;
    __syncthreads();   // smB / sqB free (prev filter done)
    { // stage hB: 128 rows x 128 cols
      int r = t >> 2, o = (t & 3) * 32;
      #pragma unroll
      for (int q = 0; q < 4; ++q)
        *(bf16x8*)&hB[r*HSTRIDE + o + q*8] =
            *(const bf16x8*)&hib[(size_t)(j0 + r)*HSTRIDE + o + q*8];
    }
    if (t < 128) sqB[t] = sq[j0 + t];
    __syncthreads();

    f32x4 acc00 = {0,0,0,0}, acc01 = {0,0,0,0}, acc10 = {0,0,0,0}, acc11 = {0,0,0,0};
    #pragma unroll
    for (int kb = 0; kb < 4; ++kb) {
      const int cbase = kb*32 + l4*8;
      bf16x8 a0 = *(const bf16x8*)&hiA[(32*wi      + l15)*HSTRIDE + cbase];
      bf16x8 a1 = *(const bf16x8*)&hiA[(32*wi + 16 + l15)*HSTRIDE + cbase];
      bf16x8 b0 = *(const bf16x8*)&hB [(32*wj      + l15)*HSTRIDE + cbase];
      bf16x8 b1 = *(const bf16x8*)&hB [(32*wj + 16 + l15)*HSTRIDE + cbase];
      acc00 = __builtin_amdgcn_mfma_f32_16x16x32_bf16(a0, b0, acc00, 0, 0, 0);
      acc01 = __builtin_amdgcn_mfma_f32_16x16x32_bf16(a0, b1, acc01, 0, 0, 0);
      acc10 = __builtin_amdgcn_mfma_f32_16x16x32_bf16(a1, b0, acc10, 0, 0, 0);
      acc11 = __builtin_amdgcn_mfma_f32_16x16x32_bf16(a1, b1, acc11, 0, 0, 0);
    }

    if (jt == 0) {
      __syncthreads();   // all waves done reading hB -> reuse as dstage
      #pragma unroll
      for (int ib = 0; ib < 2; ++ib)
        #pragma unroll
        for (int jb = 0; jb < 2; ++jb) {
          const f32x4 a = ib ? (jb ? acc11 : acc10) : (jb ? acc01 : acc00);
          #pragma unroll
          for (int r = 0; r < 4; ++r) {
            int il = 32*wi + 16*ib + l4*4 + r;
            int jl = 32*wj + 16*jb + l15;
            dstage[il*132 + jl] = sqA[il] + sqB[jl] - 2.f*a[r];
          }
        }
      __syncthreads();
      { // tau[row] = 6th smallest of 128
        int row = wave*8;
        for (int rr = 0; rr < 8; ++rr, ++row) {
          float v0 = dstage[row*132 + lane];
          float v1 = dstage[row*132 + 64 + lane];
          float t6 = 0.f;
          #pragma unroll
          for (int r6 = 0; r6 < 6; ++r6) {
            float mv; int mi;
            if (v0 <= v1) { mv = v0; mi = lane; } else { mv = v1; mi = 64 + lane; }
            #pragma unroll
            for (int s2 = 1; s2 < 64; s2 <<= 1) {
              float ov = __shfl_xor(mv, s2, 64);
              int   oi = __shfl_xor(mi, s2, 64);
              if (ov < mv || (ov == mv && oi < mi)) { mv = ov; mi = oi; }
            }
            t6 = mv;
            if (mi == lane)      v0 = 3.0e38f;
            if (mi == 64 + lane) v1 = 3.0e38f;
          }
          if (lane == 0) tauS[row] = t6;
        }
      }
      __syncthreads();
      { // filter jt0 from dstage
        int row = t >> 3, cb = (t & 7) * 16;
        float tv = tauS[row];
        size_t rg = (size_t)(b*Nn + i0 + row);
        #pragma unroll 1
        for (int c = 0; c < 16; ++c) {
          float dv = dstage[row*132 + cb + c];
          if (dv < tv) {
            int pos = atomicAdd(&cnt[row], 1);
            if (pos < CAP) cand[rg*CAPMAX + pos] = (unsigned short)(cb + c);
          }
        }
      }
    } else {
      // filter from acc regs
      #pragma unroll
      for (int ib = 0; ib < 2; ++ib)
        #pragma unroll
        for (int jb = 0; jb < 2; ++jb) {
          const f32x4 a = ib ? (jb ? acc11 : acc10) : (jb ? acc01 : acc00);
          #pragma unroll
          for (int r = 0; r < 4; ++r) {
            int il = 32*wi + 16*ib + l4*4 + r;
            int jl = 32*wj + 16*jb + l15;
            float dv = sqA[il] + sqB[jl] - 2.f*a[r];
            if (dv < tauS[il]) {
              int pos = atomicAdd(&cnt[il], 1);
              if (pos < CAP)
                cand[(size_t)(b*Nn + i0 + il)*CAPMAX + pos] = (unsigned short)(j0 + jl);
            }
          }
        }
    }
  }
  __syncthreads();
  if (t < 64) cnt_g[b*Nn + i0 + t] = cnt[t];
}

// ---------------------------------------------------------------------------
// Kernel 5: exact fp32 refine — gather reshaped for coalescing.
// 8 lanes per candidate row: lane = slot*8 + chunk; each load instr covers
// 8 rows x 128B contiguous (8 segments, not 64). Butterfly over 3 bits.
__global__ __launch_bounds__(256) void k_refine(float* __restrict__ ws,
    const unsigned short* __restrict__ cand, const int* __restrict__ cnt_g,
    int CAP) {
  __shared__ float dsh[4][CAPMAX];
  __shared__ unsigned short cjs[4][CAPMAX];
  const int wave = threadIdx.x >> 6, lane = threadIdx.x & 63;
  const int s8 = lane >> 3, ch = lane & 7;      // candidate slot, 16B chunk
  const int row = blockIdx.x*4 + wave;
  const int b = row >> 11;
  const float* __restrict__ h = ws + HOFF;
  int c_ = cnt_g[row];
  int cm = (c_ < 17 || c_ > CAP) ? 0 : c_;
  for (int cc = lane; cc < cm; cc += 64)
    cjs[wave][cc] = cand[(size_t)row*CAPMAX + cc];
  // central row fragment: floats {ch*4 + q*32 .. +3}
  float4 hi4[4];
  #pragma unroll
  for (int q = 0; q < 4; ++q)
    hi4[q] = *(const float4*)&h[(size_t)row*Cc + ch*4 + q*32];
  __syncthreads();
  const int np8 = (cm + 7) >> 3;
  for (int p = 0; p < np8; ++p) {
    int slot = p*8 + s8;
    int sl = slot < cm ? slot : 0;
    int jj = cjs[wave][sl];                     // 8-lane broadcast
    const float* hj = h + (size_t)(b*Nn + jj)*Cc;
    float part = 0.f;
    #pragma unroll
    for (int q = 0; q < 4; ++q) {
      float4 v = *(const float4*)&hj[ch*4 + q*32];
      float e0 = hi4[q].x - v.x, e1 = hi4[q].y - v.y;
      float e2 = hi4[q].z - v.z, e3 = hi4[q].w - v.w;
      part = fmaf(e0, e0, part); part = fmaf(e1, e1, part);
      part = fmaf(e2, e2, part); part = fmaf(e3, e3, part);
    }
    part += __shfl_xor(part, 1, 64);
    part += __shfl_xor(part, 2, 64);
    part += __shfl_xor(part, 4, 64);
    if (ch == 0 && slot < cm) dsh[wave][slot] = part;
  }
  __syncthreads();
  int* op = (int*)(ws + IXOFF) + (size_t)row*KK;
  for (int cc = lane; cc < cm; cc += 64) {
    float dc = dsh[wave][cc];
    int jc = cjs[wave][cc];
    int rank = 0;
    #pragma unroll 1
    for (int m = 0; m < cm; ++m) {
      float dm = dsh[wave][m];
      int jm = cjs[wave][m];
      rank += (dm < dc || (dm == dc && jm < jc)) ? 1 : 0;
    }
    if (rank >= 1 && rank <= 16) op[rank - 1] = b*Nn + jc;
  }
}

// ---------------------------------------------------------------------------
// Kernel 6: fallback exact full-scan, broadcast form (coalesced, uniform).
// Lanes own channels; per j: coalesced load + butterfly reduce; all lanes
// keep identical top-17 state -> zero divergence in the insert.
__global__ __launch_bounds__(256) void k_fb(float* __restrict__ ws,
    const int* __restrict__ cnt_g, int CAP) {
  const int wave = threadIdx.x >> 6, lane = threadIdx.x & 63;
  const int row = blockIdx.x*4 + wave;
  int c_ = cnt_g[row];
  if (c_ >= 17 && c_ <= CAP) return;   // wave-uniform; no barriers in kernel
  const int b = row >> 11;
  const float* __restrict__ h = ws + HOFF + (size_t)b*Nn*Cc;
  float hi0 = h[(size_t)(row & (Nn-1))*Cc + lane];
  float hi1 = h[(size_t)(row & (Nn-1))*Cc + lane + 64];
  float td[17]; int tj[17];
  #pragma unroll
  for (int s = 0; s < 17; ++s) { td[s] = 3.0e38f; tj[s] = 0x7FFFFFFF; }
  float cmax = 3.0e38f; int cjm = 0x7FFFFFFF, cpos = 0;
  for (int j = 0; j < Nn; ++j) {
    float a0 = h[(size_t)j*Cc + lane];
    float a1 = h[(size_t)j*Cc + lane + 64];
    float e0 = hi0 - a0, e1 = hi1 - a1;
    float part = e0*e0;
    part = fmaf(e1, e1, part);
    #pragma unroll
    for (int s2 = 1; s2 < 64; s2 <<= 1) part += __shfl_xor(part, s2, 64);
    float d = part;                       // identical on all lanes
    if (d < cmax || (d == cmax && j < cjm)) {
      #pragma unroll
      for (int s = 0; s < 17; ++s) {
        bool r = (s == cpos);
        td[s] = r ? d : td[s];
        tj[s] = r ? j : tj[s];
      }
      cmax = td[0]; cjm = tj[0]; cpos = 0;
      #pragma unroll
      for (int s = 1; s < 17; ++s)
        if (td[s] > cmax || (td[s] == cmax && tj[s] > cjm)) {
          cmax = td[s]; cjm = tj[s]; cpos = s;
        }
    }
  }
  // extract in lex order; round 0 = self, rounds 1..16 -> op
  int* op = (int*)(ws + IXOFF) + (size_t)row*KK;
  #pragma unroll 1
  for (int r17 = 0; r17 < 17; ++r17) {
    float mv = td[0]; int mj = tj[0], mp = 0;
    #pragma unroll
    for (int s = 1; s < 17; ++s)
      if (td[s] < mv || (td[s] == mv && tj[s] < mj)) { mv = td[s]; mj = tj[s]; mp = s; }
    td[mp] = 3.0e38f; tj[mp] = 0x7FFFFFFF;
    if (r17 >= 1 && lane == 0) op[r17 - 1] = b*Nn + mj;
  }
}

// ---------------------------------------------------------------------------
// Kernel 7: fused per-point MLP + softmax + aggregate + residual.
__global__ __launch_bounds__(64) void k_mlp(
    const float* __restrict__ b1v, const float* __restrict__ W2,
    const float* __restrict__ Wx2, const float* __restrict__ bx2,
    const float* __restrict__ x, float* __restrict__ out,
    float* __restrict__ ws) {
  __shared__ float hw_s[64][20];
  __shared__ float hx_s[128][20];
  __shared__ int mk[16];
  const int n = blockIdx.x;
  const int b = n >> 11;
  const int t = threadIdx.x;
  const int* __restrict__ ip = (const int*)(ws + IXOFF) + (size_t)n*KK;
  if (t < 16) mk[t] = ip[t];
  __syncthreads();
  {
    const float* A1 = ws + A1OFF;
    float a1n = A1[(size_t)n*F2 + t];
    float bb  = b1v[t];
    #pragma unroll
    for (int k = 0; k < 16; ++k) {
      float v = A1[(size_t)mk[k]*F2 + t] - a1n + bb;
      v = (v > 0.f ? v : 0.2f*v) * SQ2;
      hw_s[t][k] = v;
    }
  }
  __syncthreads();
  float wlA[16], wlB[16];
  #pragma unroll
  for (int k = 0; k < 16; ++k) { wlA[k] = 0.f; wlB[k] = 0.f; }
  for (int j = 0; j < 64; ++j) {
    float w2a = W2[j*FO + t];
    float w2b = W2[j*FO + t + 64];
    const float4* hp = (const float4*)(&hw_s[j][0]);
    float4 q0 = hp[0], q1 = hp[1], q2 = hp[2], q3 = hp[3];
    float hv[16] = {q0.x,q0.y,q0.z,q0.w, q1.x,q1.y,q1.z,q1.w,
                    q2.x,q2.y,q2.z,q2.w, q3.x,q3.y,q3.z,q3.w};
    #pragma unroll
    for (int k = 0; k < 16; ++k) {
      wlA[k] = fmaf(hv[k], w2a, wlA[k]);
      wlB[k] = fmaf(hv[k], w2b, wlB[k]);
    }
  }
  {
    float mA = wlA[0], mB = wlB[0];
    #pragma unroll
    for (int k = 1; k < 16; ++k) { mA = fmaxf(mA, wlA[k]); mB = fmaxf(mB, wlB[k]); }
    float sA = 0.f, sB = 0.f;
    #pragma unroll
    for (int k = 0; k < 16; ++k) {
      wlA[k] = __expf(wlA[k] - mA); sA += wlA[k];
      wlB[k] = __expf(wlB[k] - mB); sB += wlB[k];
    }
    float rA = 1.0f/sA, rB = 1.0f/sB;
    #pragma unroll
    for (int k = 0; k < 16; ++k) { wlA[k] *= rA; wlB[k] *= rB; }
  }
  {
    const float* Ad = ws + ADOFF;
    float hbA = ws[HXOFF + (size_t)n*Cc + t];
    float hbB = ws[HXOFF + (size_t)n*Cc + t + 64];
    #pragma unroll
    for (int k = 0; k < 16; ++k) {
      size_t mo = (size_t)mk[k]*Cc;
      float vA = hbA + Ad[mo + t];
      float vB = hbB + Ad[mo + t + 64];
      vA = (vA > 0.f ? vA : 0.2f*vA) * SQ2;
      vB = (vB > 0.f ? vB : 0.2f*vB) * SQ2;
      hx_s[t][k]      = vA;
      hx_s[t + 64][k] = vB;
    }
  }
  __syncthreads();
  float xeA[16], xeB[16];
  #pragma unroll
  for (int k = 0; k < 16; ++k) { xeA[k] = 0.f; xeB[k] = 0.f; }
  for (int j = 0; j < 128; ++j) {
    float wxa = Wx2[j*FO + t];
    float wxb = Wx2[j*FO + t + 64];
    const float4* hp = (const float4*)(&hx_s[j][0]);
    float4 q0 = hp[0], q1 = hp[1], q2 = hp[2], q3 = hp[3];
    float hv[16] = {q0.x,q0.y,q0.z,q0.w, q1.x,q1.y,q1.z,q1.w,
                    q2.x,q2.y,q2.z,q2.w, q3.x,q3.y,q3.z,q3.w};
    #pragma unroll
    for (int k = 0; k < 16; ++k) {
      xeA[k] = fmaf(hv[k], wxa, xeA[k]);
      xeB[k] = fmaf(hv[k], wxb, xeB[k]);
    }
  }
  float bxa = bx2[t], bxb = bx2[t + 64];
  float aggA = 0.f, aggB = 0.f;
  #pragma unroll
  for (int k = 0; k < 16; ++k) {
    aggA = fmaf(xeA[k] + bxa, wlA[k], aggA);
    aggB = fmaf(xeB[k] + bxb, wlB[k], aggB);
  }
  float lsA = ws[LSOFF + b*Cc + t];
  float lsB = ws[LSOFF + b*Cc + t + 64];
  size_t xo = (size_t)n*Cc;
  out[xo + t]      = fmaf(aggA, lsA, x[xo + t]);
  out[xo + t + 64] = fmaf(aggB, lsB, x[xo + t + 64]);
}

// ---------------------------------------------------------------------------
extern "C" void kernel_launch(void* const* d_in, const int* in_sizes, int n_in,
                              void* d_out, int out_size, void* d_ws, size_t ws_size,
                              hipStream_t stream) {
  const float* x   = (const float*)d_in[0];
  const float* w   = (const float*)d_in[1];
  const float* Wg  = (const float*)d_in[2];
  const float* Wb  = (const float*)d_in[3];
  const float* W1  = (const float*)d_in[4];
  const float* b1  = (const float*)d_in[5];
  const float* W2  = (const float*)d_in[6];
  const float* Wx1 = (const float*)d_in[8];
  const float* bx1 = (const float*)d_in[9];
  const float* Wx2 = (const float*)d_in[10];
  const float* bx2 = (const float*)d_in[11];
  const float* Wls = (const float*)d_in[12];
  const float* bls = (const float*)d_in[13];
  float* out = (float*)d_out;
  float* ws  = (float*)d_ws;
  unsigned short* hi_g = (unsigned short*)((char*)d_ws + HIBYTES);
  unsigned short* cand = (unsigned short*)((char*)d_ws + CANDBYTES);
  int* cnt_g = (int*)(ws + CNTOFF);

  int CAP = 0;
  if (ws_size > CANDBYTES) {
    size_t c = (ws_size - CANDBYTES) / ((size_t)NP * 2);
    CAP = (c >= CAPMAX) ? CAPMAX : (int)c;
  }

  k_pervec<<<Bz, 512, 0, stream>>>(w, Wg, Wb, Wls, bls, ws);
  k_h<<<NP, 64, 0, stream>>>(x, ws, hi_g);
  k_pre<<<NP/4, 128, 0, stream>>>(W1, Wx1, bx1, ws);
  k_filter<<<256, 512, 0, stream>>>(ws, hi_g, cand, cnt_g, CAP);
  k_refine<<<NP/4, 256, 0, stream>>>(ws, cand, cnt_g, CAP);
  k_fb<<<NP/4, 256, 0, stream>>>(ws, cnt_g, CAP);
  k_mlp<<<NP, 64, 0, stream>>>(b1, W2, Wx2, bx2, x, out, ws);
}

// Round 5
// 995.342 us; speedup vs baseline: 1.6300x; 1.6300x over previous
//
#include <hip/hip_runtime.h>

#define Bz 8
#define Nn 2048
#define Cc 128
#define KK 16
#define WD 512
#define F2 64
#define FO 128
#define NP (Bz*Nn)
#define SQ2 1.41421356237309515f
#define HSTRIDE 136   // padded bf16 row stride (16B-aligned)
#define CAPMAX 256

// ws layout (float offsets)
#define GOFF   ((size_t)0)
#define BEOFF  ((size_t)1024)
#define LSOFF  ((size_t)2048)
#define HOFF   ((size_t)3072)
#define SQOFF  (HOFF + (size_t)NP*Cc)
#define A1OFF  (SQOFF + (size_t)NP)
#define ADOFF  (A1OFF + (size_t)NP*F2)
#define HXOFF  (ADOFF + (size_t)NP*Cc)
#define IXOFF  (HXOFF + (size_t)NP*Cc)
#define CNTOFF (IXOFF + (size_t)NP*KK)
#define FBNOFF (CNTOFF + (size_t)NP)
#define FBQOFF (FBNOFF + (size_t)64)
// byte offsets for the u16 arrays
#define HIBYTES   ((FBQOFF + (size_t)NP) * 4)
#define CANDBYTES (HIBYTES + (size_t)NP*HSTRIDE*2)

typedef __attribute__((ext_vector_type(8))) short bf16x8;
typedef __attribute__((ext_vector_type(4))) float f32x4;

__device__ __forceinline__ unsigned short f2bf(float f) {
  unsigned u = __float_as_uint(f);
  unsigned r = (u + 0x7FFFu + ((u >> 16) & 1u)) >> 16;
  return (unsigned short)r;
}

// ---------------------------------------------------------------------------
// Kernel 1: per-batch FiLM vectors
__global__ __launch_bounds__(512) void k_pervec(const float* __restrict__ w,
    const float* __restrict__ Wg, const float* __restrict__ Wb,
    const float* __restrict__ Wls, const float* __restrict__ bls,
    float* __restrict__ ws) {
  __shared__ float red[3][4][Cc];
  const int b = blockIdx.x;
  const int c = threadIdx.x & 127, dc = threadIdx.x >> 7;
  const float* wr = w + b*WD;
  float ag = 0.f, ab = 0.f, al = 0.f;
  for (int d = dc*128; d < dc*128 + 128; ++d) {
    float wv = wr[d];
    ag = fmaf(wv, Wg[d*Cc + c], ag);
    ab = fmaf(wv, Wb[d*Cc + c], ab);
    al = fmaf(wv, Wls[d*Cc + c], al);
  }
  red[0][dc][c] = ag; red[1][dc][c] = ab; red[2][dc][c] = al;
  __syncthreads();
  if (dc == 0) {
    float sg = red[0][0][c] + red[0][1][c] + red[0][2][c] + red[0][3][c];
    float sb = red[1][0][c] + red[1][1][c] + red[1][2][c] + red[1][3][c];
    float sl = red[2][0][c] + red[2][1][c] + red[2][2][c] + red[2][3][c];
    ws[GOFF  + b*Cc + c] = 1.0f + sg;
    ws[BEOFF + b*Cc + c] = sb;
    ws[LSOFF + b*Cc + c] = sl + bls[c];
  }
}

// ---------------------------------------------------------------------------
// Kernel 2: h = LN(x)*g + beta, sq = sum(h*h), hi = bf16(h); zero fb queue.
__global__ __launch_bounds__(64) void k_h(const float* __restrict__ x,
                                          float* __restrict__ ws,
                                          unsigned short* __restrict__ hi_g,
                                          int* __restrict__ fbn) {
  const int n = blockIdx.x;
  const int b = n >> 11;
  const int t = threadIdx.x;
  if (n == 0 && t == 0) fbn[0] = 0;
  const float* xr = x + (size_t)n*Cc;
  float x0 = xr[t], x1 = xr[t + 64];
  float s = x0 + x1, ss = x0*x0 + x1*x1;
  #pragma unroll
  for (int m = 1; m < 64; m <<= 1) {
    s  += __shfl_xor(s,  m, 64);
    ss += __shfl_xor(ss, m, 64);
  }
  float mu  = s * (1.0f/128.0f);
  float var = ss * (1.0f/128.0f) - mu*mu;
  float rs  = rsqrtf(var + 1e-5f);
  float h0 = (x0 - mu)*rs*ws[GOFF + b*Cc + t]      + ws[BEOFF + b*Cc + t];
  float h1 = (x1 - mu)*rs*ws[GOFF + b*Cc + t + 64] + ws[BEOFF + b*Cc + t + 64];
  float* hr = ws + HOFF + (size_t)n*Cc;
  hr[t] = h0; hr[t + 64] = h1;
  hi_g[(size_t)n*HSTRIDE + t]      = f2bf(h0);
  hi_g[(size_t)n*HSTRIDE + t + 64] = f2bf(h1);
  float q = h0*h0 + h1*h1;
  #pragma unroll
  for (int m = 1; m < 64; m <<= 1) q += __shfl_xor(q, m, 64);
  if (t == 0) ws[SQOFF + n] = q;
}

// ---------------------------------------------------------------------------
// Kernel 3: precompute A1 = h@W1, Ad = h@Wx1[128:], hxb = h@Wx1[:128]-Ad+bx1
__global__ __launch_bounds__(128) void k_pre(const float* __restrict__ W1,
    const float* __restrict__ Wx1, const float* __restrict__ bx1,
    float* __restrict__ ws) {
  __shared__ float hs[4][Cc];
  const int t = threadIdx.x;
  const size_t row0 = (size_t)blockIdx.x * 4;
  const float* h = ws + HOFF;
  #pragma unroll
  for (int r = 0; r < 4; ++r) hs[r][t] = h[(row0 + r)*Cc + t];
  __syncthreads();
  float ad[4] = {0,0,0,0}, ac[4] = {0,0,0,0};
  for (int cp = 0; cp < Cc; ++cp) {
    float whi = Wx1[cp*FO + t];
    float wlo = Wx1[(Cc + cp)*FO + t];
    #pragma unroll
    for (int r = 0; r < 4; ++r) {
      float hv = hs[r][cp];
      ac[r] = fmaf(hv, whi, ac[r]);
      ad[r] = fmaf(hv, wlo, ad[r]);
    }
  }
  float bx = bx1[t];
  #pragma unroll
  for (int r = 0; r < 4; ++r) {
    ws[ADOFF + (row0 + r)*Cc + t] = ad[r];
    ws[HXOFF + (row0 + r)*Cc + t] = ac[r] - ad[r] + bx;
  }
  const int j = t & 63, rp = t >> 6;
  float a0 = 0.f, a1 = 0.f;
  for (int cp = 0; cp < Cc; ++cp) {
    float wv = W1[cp*F2 + j];
    a0 = fmaf(hs[rp][cp],     wv, a0);
    a1 = fmaf(hs[rp + 2][cp], wv, a1);
  }
  ws[A1OFF + (row0 + rp)*F2 + j]     = a0;
  ws[A1OFF + (row0 + rp + 2)*F2 + j] = a1;
}

// ---------------------------------------------------------------------------
// Kernel 4: MFMA approx distances + tau-filter compaction.
// tau = 18th smallest of j-tiles {0,1} (256 samples) => cnt >= 17 guaranteed.
__global__ __launch_bounds__(512, 1) void k_filter(float* __restrict__ ws,
    const unsigned short* __restrict__ hi_g, unsigned short* __restrict__ cand,
    int* __restrict__ cnt_g, int CAP) {
  __shared__ unsigned short hiA[64*HSTRIDE];   // 17408 B
  __shared__ float smB[8704];                  // hB u16[128*136] / dstage f32[64*132]
  __shared__ float t18[64][2][18];             // 9216 B
  __shared__ float sqA[64], sqB[128], tauS[64];
  __shared__ int cnt[64];
  unsigned short* hB = (unsigned short*)smB;
  float* dstage = smB;                         // stride 132
  const int t = threadIdx.x;
  const int b = blockIdx.x >> 5;
  const int i0 = (blockIdx.x & 31) << 6;
  const int wave = t >> 6, lane = t & 63;
  const int wi = wave & 1, wj = wave >> 1;     // wj 0..3
  const int l15 = lane & 15, l4 = lane >> 4;
  const float* __restrict__ sq = ws + SQOFF + (size_t)b*Nn;
  const unsigned short* __restrict__ hib = hi_g + (size_t)b*Nn*HSTRIDE;

  { // load hiA: 64 rows x 128 cols
    int r = t >> 3, o = (t & 7) * 16;
    *(bf16x8*)&hiA[r*HSTRIDE + o]     = *(const bf16x8*)&hib[(size_t)(i0 + r)*HSTRIDE + o];
    *(bf16x8*)&hiA[r*HSTRIDE + o + 8] = *(const bf16x8*)&hib[(size_t)(i0 + r)*HSTRIDE + o + 8];
  }
  if (t < 64) { sqA[t] = sq[i0 + t]; cnt[t] = 0; }

  // ---- tau pre-pass over j-tiles 0,1 ----
  for (int jt = 0; jt < 2; ++jt) {
    const int j0 = jt << 7;
    __syncthreads();
    { int r = t >> 2, o = (t & 3) * 32;
      #pragma unroll
      for (int q = 0; q < 4; ++q)
        *(bf16x8*)&hB[r*HSTRIDE + o + q*8] =
            *(const bf16x8*)&hib[(size_t)(j0 + r)*HSTRIDE + o + q*8];
    }
    if (t < 128) sqB[t] = sq[j0 + t];
    __syncthreads();
    f32x4 acc00 = {0,0,0,0}, acc01 = {0,0,0,0}, acc10 = {0,0,0,0}, acc11 = {0,0,0,0};
    #pragma unroll
    for (int kb = 0; kb < 4; ++kb) {
      const int cbase = kb*32 + l4*8;
      bf16x8 a0 = *(const bf16x8*)&hiA[(32*wi      + l15)*HSTRIDE + cbase];
      bf16x8 a1 = *(const bf16x8*)&hiA[(32*wi + 16 + l15)*HSTRIDE + cbase];
      bf16x8 b0 = *(const bf16x8*)&hB [(32*wj      + l15)*HSTRIDE + cbase];
      bf16x8 b1 = *(const bf16x8*)&hB [(32*wj + 16 + l15)*HSTRIDE + cbase];
      acc00 = __builtin_amdgcn_mfma_f32_16x16x32_bf16(a0, b0, acc00, 0, 0, 0);
      acc01 = __builtin_amdgcn_mfma_f32_16x16x32_bf16(a0, b1, acc01, 0, 0, 0);
      acc10 = __builtin_amdgcn_mfma_f32_16x16x32_bf16(a1, b0, acc10, 0, 0, 0);
      acc11 = __builtin_amdgcn_mfma_f32_16x16x32_bf16(a1, b1, acc11, 0, 0, 0);
    }
    __syncthreads();   // hB reads done -> reuse smB as dstage
    #pragma unroll
    for (int ib = 0; ib < 2; ++ib)
      #pragma unroll
      for (int jb = 0; jb < 2; ++jb) {
        const f32x4 a = ib ? (jb ? acc11 : acc10) : (jb ? acc01 : acc00);
        #pragma unroll
        for (int r = 0; r < 4; ++r) {
          int il = 32*wi + 16*ib + l4*4 + r;
          int jl = 32*wj + 16*jb + l15;
          dstage[il*132 + jl] = sqA[il] + sqB[jl] - 2.f*a[r];
        }
      }
    __syncthreads();
    { // per row: 18 smallest (ascending) of this tile's 128
      int row = wave*8;
      for (int rr = 0; rr < 8; ++rr, ++row) {
        float v0 = dstage[row*132 + lane];
        float v1 = dstage[row*132 + 64 + lane];
        #pragma unroll 1
        for (int r6 = 0; r6 < 18; ++r6) {
          float mv; int mi;
          if (v0 <= v1) { mv = v0; mi = lane; } else { mv = v1; mi = 64 + lane; }
          #pragma unroll
          for (int s2 = 1; s2 < 64; s2 <<= 1) {
            float ov = __shfl_xor(mv, s2, 64);
            int   oi = __shfl_xor(mi, s2, 64);
            if (ov < mv || (ov == mv && oi < mi)) { mv = ov; mi = oi; }
          }
          if (lane == 0) t18[row][jt][r6] = mv;
          if (mi == lane)      v0 = 3.0e38f;
          if (mi == 64 + lane) v1 = 3.0e38f;
        }
      }
    }
  }
  __syncthreads();
  if (t < 64) {  // merge two ascending 18-lists -> 18th smallest of 256-sample
    int p0 = 0, p1 = 0; float tv = 0.f;
    #pragma unroll 1
    for (int s = 0; s < 18; ++s) {
      float a = (p0 < 18) ? t18[t][0][p0] : 3.0e38f;
      float c = (p1 < 18) ? t18[t][1][p1] : 3.0e38f;
      if (a <= c) { tv = a; ++p0; } else { tv = c; ++p1; }
    }
    tauS[t] = tv;
  }

  // ---- main pass: all 16 j-tiles, filter from regs ----
  for (int jt = 0; jt < 16; ++jt) {
    const int j0 = jt << 7;
    __syncthreads();   // prior filter's sqB reads + MFMA hB reads done
    { int r = t >> 2, o = (t & 3) * 32;
      #pragma unroll
      for (int q = 0; q < 4; ++q)
        *(bf16x8*)&hB[r*HSTRIDE + o + q*8] =
            *(const bf16x8*)&hib[(size_t)(j0 + r)*HSTRIDE + o + q*8];
    }
    if (t < 128) sqB[t] = sq[j0 + t];
    __syncthreads();
    f32x4 acc00 = {0,0,0,0}, acc01 = {0,0,0,0}, acc10 = {0,0,0,0}, acc11 = {0,0,0,0};
    #pragma unroll
    for (int kb = 0; kb < 4; ++kb) {
      const int cbase = kb*32 + l4*8;
      bf16x8 a0 = *(const bf16x8*)&hiA[(32*wi      + l15)*HSTRIDE + cbase];
      bf16x8 a1 = *(const bf16x8*)&hiA[(32*wi + 16 + l15)*HSTRIDE + cbase];
      bf16x8 b0 = *(const bf16x8*)&hB [(32*wj      + l15)*HSTRIDE + cbase];
      bf16x8 b1 = *(const bf16x8*)&hB [(32*wj + 16 + l15)*HSTRIDE + cbase];
      acc00 = __builtin_amdgcn_mfma_f32_16x16x32_bf16(a0, b0, acc00, 0, 0, 0);
      acc01 = __builtin_amdgcn_mfma_f32_16x16x32_bf16(a0, b1, acc01, 0, 0, 0);
      acc10 = __builtin_amdgcn_mfma_f32_16x16x32_bf16(a1, b0, acc10, 0, 0, 0);
      acc11 = __builtin_amdgcn_mfma_f32_16x16x32_bf16(a1, b1, acc11, 0, 0, 0);
    }
    #pragma unroll
    for (int ib = 0; ib < 2; ++ib)
      #pragma unroll
      for (int jb = 0; jb < 2; ++jb) {
        const f32x4 a = ib ? (jb ? acc11 : acc10) : (jb ? acc01 : acc00);
        #pragma unroll
        for (int r = 0; r < 4; ++r) {
          int il = 32*wi + 16*ib + l4*4 + r;
          int jl = 32*wj + 16*jb + l15;
          float dv = sqA[il] + sqB[jl] - 2.f*a[r];
          if (dv < tauS[il]) {
            int pos = atomicAdd(&cnt[il], 1);
            if (pos < CAP)
              cand[(size_t)(b*Nn + i0 + il)*CAPMAX + pos] = (unsigned short)(j0 + jl);
          }
        }
      }
  }
  __syncthreads();
  if (t < 64) cnt_g[b*Nn + i0 + t] = cnt[t];
}

// ---------------------------------------------------------------------------
// Kernel 5: exact fp32 refine (8 lanes per candidate row) + fb-queue append.
__global__ __launch_bounds__(256) void k_refine(float* __restrict__ ws,
    const unsigned short* __restrict__ cand, const int* __restrict__ cnt_g,
    int* __restrict__ fbn, int* __restrict__ fbq, int CAP) {
  __shared__ float dsh[4][CAPMAX];
  __shared__ unsigned short cjs[4][CAPMAX];
  const int wave = threadIdx.x >> 6, lane = threadIdx.x & 63;
  const int s8 = lane >> 3, ch = lane & 7;
  const int row = blockIdx.x*4 + wave;
  const int b = row >> 11;
  const float* __restrict__ h = ws + HOFF;
  int c_ = cnt_g[row];
  int cm = (c_ < 17 || c_ > CAP) ? 0 : c_;
  if (cm == 0 && lane == 0) { int q = atomicAdd(fbn, 1); fbq[q] = row; }
  for (int cc = lane; cc < cm; cc += 64)
    cjs[wave][cc] = cand[(size_t)row*CAPMAX + cc];
  float4 hi4[4];
  #pragma unroll
  for (int q = 0; q < 4; ++q)
    hi4[q] = *(const float4*)&h[(size_t)row*Cc + ch*4 + q*32];
  __syncthreads();
  const int np8 = (cm + 7) >> 3;
  for (int p = 0; p < np8; ++p) {
    int slot = p*8 + s8;
    int sl = slot < cm ? slot : 0;
    int jj = cjs[wave][sl];
    const float* hj = h + (size_t)(b*Nn + jj)*Cc;
    float part = 0.f;
    #pragma unroll
    for (int q = 0; q < 4; ++q) {
      float4 v = *(const float4*)&hj[ch*4 + q*32];
      float e0 = hi4[q].x - v.x, e1 = hi4[q].y - v.y;
      float e2 = hi4[q].z - v.z, e3 = hi4[q].w - v.w;
      part = fmaf(e0, e0, part); part = fmaf(e1, e1, part);
      part = fmaf(e2, e2, part); part = fmaf(e3, e3, part);
    }
    part += __shfl_xor(part, 1, 64);
    part += __shfl_xor(part, 2, 64);
    part += __shfl_xor(part, 4, 64);
    if (ch == 0 && slot < cm) dsh[wave][slot] = part;
  }
  __syncthreads();
  int* op = (int*)(ws + IXOFF) + (size_t)row*KK;
  for (int cc = lane; cc < cm; cc += 64) {
    float dc = dsh[wave][cc];
    int jc = cjs[wave][cc];
    int rank = 0;
    #pragma unroll 1
    for (int m = 0; m < cm; ++m) {
      float dm = dsh[wave][m];
      int jm = cjs[wave][m];
      rank += (dm < dc || (dm == dc && jm < jc)) ? 1 : 0;
    }
    if (rank >= 1 && rank <= 16) op[rank - 1] = b*Nn + jc;
  }
}

// ---------------------------------------------------------------------------
// Kernel 6: fallback — queue-driven, one block per row, 4 waves x 512 j.
__global__ __launch_bounds__(256) void k_fb(float* __restrict__ ws,
    const int* __restrict__ fbn, const int* __restrict__ fbq) {
  __shared__ float fd[4][17];
  __shared__ int   fj[4][17];
  __shared__ float his[128];
  const int wave = threadIdx.x >> 6, lane = threadIdx.x & 63;
  const int nfb = fbn[0];
  for (int q = blockIdx.x; q < nfb; q += gridDim.x) {
    const int row = fbq[q];
    const int b = row >> 11;
    const float* __restrict__ h = ws + HOFF + (size_t)b*Nn*Cc;
    if (threadIdx.x < 128) his[threadIdx.x] = h[(size_t)(row & (Nn-1))*Cc + threadIdx.x];
    __syncthreads();
    const float hi0 = his[lane], hi1 = his[lane + 64];
    float td[17]; int tj[17];
    #pragma unroll
    for (int s = 0; s < 17; ++s) { td[s] = 3.0e38f; tj[s] = 0x7FFFFFFF; }
    float cmax = 3.0e38f; int cjm = 0x7FFFFFFF, cpos = 0;
    const int jb = wave*512;
    #pragma unroll 1
    for (int it = 0; it < 256; ++it) {
      int j = jb + it*2;
      float a0 = h[(size_t)j*Cc + lane],       a1 = h[(size_t)j*Cc + lane + 64];
      float b0 = h[(size_t)(j+1)*Cc + lane],   b1 = h[(size_t)(j+1)*Cc + lane + 64];
      float e0 = hi0 - a0, e1 = hi1 - a1, f0 = hi0 - b0, f1 = hi1 - b1;
      float p0 = e0*e0; p0 = fmaf(e1, e1, p0);
      float p1 = f0*f0; p1 = fmaf(f1, f1, p1);
      #pragma unroll
      for (int s2 = 1; s2 < 64; s2 <<= 1) {
        p0 += __shfl_xor(p0, s2, 64);
        p1 += __shfl_xor(p1, s2, 64);
      }
      #pragma unroll
      for (int u = 0; u < 2; ++u) {
        float d = u ? p1 : p0;
        int jd = j + u;
        if (d < cmax || (d == cmax && jd < cjm)) {
          #pragma unroll
          for (int s = 0; s < 17; ++s) {
            bool r = (s == cpos);
            td[s] = r ? d  : td[s];
            tj[s] = r ? jd : tj[s];
          }
          cmax = td[0]; cjm = tj[0]; cpos = 0;
          #pragma unroll
          for (int s = 1; s < 17; ++s)
            if (td[s] > cmax || (td[s] == cmax && tj[s] > cjm)) {
              cmax = td[s]; cjm = tj[s]; cpos = s;
            }
        }
      }
    }
    if (lane == 0) {
      #pragma unroll
      for (int s = 0; s < 17; ++s) { fd[wave][s] = td[s]; fj[wave][s] = tj[s]; }
    }
    __syncthreads();
    // 68-entry rank-count merge by threads 0..67
    if (threadIdx.x < 68) {
      float dc = fd[threadIdx.x >> 4 & 3][0];  // placeholder to keep regs tidy
      int e = threadIdx.x;
      dc = fd[e >> 4 == 4 ? 3 : e / 17][e % 17];
      int  jc = fj[e / 17][e % 17];
      dc = fd[e / 17][e % 17];
      int rank = 0;
      #pragma unroll 1
      for (int m = 0; m < 68; ++m) {
        float dm = fd[m / 17][m % 17];
        int jm = fj[m / 17][m % 17];
        rank += (dm < dc || (dm == dc && jm < jc)) ? 1 : 0;
      }
      if (rank >= 1 && rank <= 16) {
        int* op = (int*)(ws + IXOFF) + (size_t)row*KK;
        op[rank - 1] = b*Nn + jc;
      }
    }
    __syncthreads();
  }
}

// ---------------------------------------------------------------------------
// Kernel 7: fused per-point MLP + softmax + aggregate + residual.
__global__ __launch_bounds__(64) void k_mlp(
    const float* __restrict__ b1v, const float* __restrict__ W2,
    const float* __restrict__ Wx2, const float* __restrict__ bx2,
    const float* __restrict__ x, float* __restrict__ out,
    float* __restrict__ ws) {
  __shared__ float hw_s[64][20];
  __shared__ float hx_s[128][20];
  __shared__ int mk[16];
  const int n = blockIdx.x;
  const int b = n >> 11;
  const int t = threadIdx.x;
  const int* __restrict__ ip = (const int*)(ws + IXOFF) + (size_t)n*KK;
  if (t < 16) mk[t] = ip[t];
  __syncthreads();
  {
    const float* A1 = ws + A1OFF;
    float a1n = A1[(size_t)n*F2 + t];
    float bb  = b1v[t];
    #pragma unroll
    for (int k = 0; k < 16; ++k) {
      float v = A1[(size_t)mk[k]*F2 + t] - a1n + bb;
      v = (v > 0.f ? v : 0.2f*v) * SQ2;
      hw_s[t][k] = v;
    }
  }
  __syncthreads();
  float wlA[16], wlB[16];
  #pragma unroll
  for (int k = 0; k < 16; ++k) { wlA[k] = 0.f; wlB[k] = 0.f; }
  for (int j = 0; j < 64; ++j) {
    float w2a = W2[j*FO + t];
    float w2b = W2[j*FO + t + 64];
    const float4* hp = (const float4*)(&hw_s[j][0]);
    float4 q0 = hp[0], q1 = hp[1], q2 = hp[2], q3 = hp[3];
    float hv[16] = {q0.x,q0.y,q0.z,q0.w, q1.x,q1.y,q1.z,q1.w,
                    q2.x,q2.y,q2.z,q2.w, q3.x,q3.y,q3.z,q3.w};
    #pragma unroll
    for (int k = 0; k < 16; ++k) {
      wlA[k] = fmaf(hv[k], w2a, wlA[k]);
      wlB[k] = fmaf(hv[k], w2b, wlB[k]);
    }
  }
  {
    float mA = wlA[0], mB = wlB[0];
    #pragma unroll
    for (int k = 1; k < 16; ++k) { mA = fmaxf(mA, wlA[k]); mB = fmaxf(mB, wlB[k]); }
    float sA = 0.f, sB = 0.f;
    #pragma unroll
    for (int k = 0; k < 16; ++k) {
      wlA[k] = __expf(wlA[k] - mA); sA += wlA[k];
      wlB[k] = __expf(wlB[k] - mB); sB += wlB[k];
    }
    float rA = 1.0f/sA, rB = 1.0f/sB;
    #pragma unroll
    for (int k = 0; k < 16; ++k) { wlA[k] *= rA; wlB[k] *= rB; }
  }
  {
    const float* Ad = ws + ADOFF;
    float hbA = ws[HXOFF + (size_t)n*Cc + t];
    float hbB = ws[HXOFF + (size_t)n*Cc + t + 64];
    #pragma unroll
    for (int k = 0; k < 16; ++k) {
      size_t mo = (size_t)mk[k]*Cc;
      float vA = hbA + Ad[mo + t];
      float vB = hbB + Ad[mo + t + 64];
      vA = (vA > 0.f ? vA : 0.2f*vA) * SQ2;
      vB = (vB > 0.f ? vB : 0.2f*vB) * SQ2;
      hx_s[t][k]      = vA;
      hx_s[t + 64][k] = vB;
    }
  }
  __syncthreads();
  float xeA[16], xeB[16];
  #pragma unroll
  for (int k = 0; k < 16; ++k) { xeA[k] = 0.f; xeB[k] = 0.f; }
  for (int j = 0; j < 128; ++j) {
    float wxa = Wx2[j*FO + t];
    float wxb = Wx2[j*FO + t + 64];
    const float4* hp = (const float4*)(&hx_s[j][0]);
    float4 q0 = hp[0], q1 = hp[1], q2 = hp[2], q3 = hp[3];
    float hv[16] = {q0.x,q0.y,q0.z,q0.w, q1.x,q1.y,q1.z,q1.w,
                    q2.x,q2.y,q2.z,q2.w, q3.x,q3.y,q3.z,q3.w};
    #pragma unroll
    for (int k = 0; k < 16; ++k) {
      xeA[k] = fmaf(hv[k], wxa, xeA[k]);
      xeB[k] = fmaf(hv[k], wxb, xeB[k]);
    }
  }
  float bxa = bx2[t], bxb = bx2[t + 64];
  float aggA = 0.f, aggB = 0.f;
  #pragma unroll
  for (int k = 0; k < 16; ++k) {
    aggA = fmaf(xeA[k] + bxa, wlA[k], aggA);
    aggB = fmaf(xeB[k] + bxb, wlB[k], aggB);
  }
  float lsA = ws[LSOFF + b*Cc + t];
  float lsB = ws[LSOFF + b*Cc + t + 64];
  size_t xo = (size_t)n*Cc;
  out[xo + t]      = fmaf(aggA, lsA, x[xo + t]);
  out[xo + t + 64] = fmaf(aggB, lsB, x[xo + t + 64]);
}

// ---------------------------------------------------------------------------
extern "C" void kernel_launch(void* const* d_in, const int* in_sizes, int n_in,
                              void* d_out, int out_size, void* d_ws, size_t ws_size,
                              hipStream_t stream) {
  const float* x   = (const float*)d_in[0];
  const float* w   = (const float*)d_in[1];
  const float* Wg  = (const float*)d_in[2];
  const float* Wb  = (const float*)d_in[3];
  const float* W1  = (const float*)d_in[4];
  const float* b1  = (const float*)d_in[5];
  const float* W2  = (const float*)d_in[6];
  const float* Wx1 = (const float*)d_in[8];
  const float* bx1 = (const float*)d_in[9];
  const float* Wx2 = (const float*)d_in[10];
  const float* bx2 = (const float*)d_in[11];
  const float* Wls = (const float*)d_in[12];
  const float* bls = (const float*)d_in[13];
  float* out = (float*)d_out;
  float* ws  = (float*)d_ws;
  unsigned short* hi_g = (unsigned short*)((char*)d_ws + HIBYTES);
  unsigned short* cand = (unsigned short*)((char*)d_ws + CANDBYTES);
  int* cnt_g = (int*)(ws + CNTOFF);
  int* fbn   = (int*)(ws + FBNOFF);
  int* fbq   = (int*)(ws + FBQOFF);

  int CAP = 0;
  if (ws_size > CANDBYTES) {
    size_t c = (ws_size - CANDBYTES) / ((size_t)NP * 2);
    CAP = (c >= CAPMAX) ? CAPMAX : (int)c;
  }

  k_pervec<<<Bz, 512, 0, stream>>>(w, Wg, Wb, Wls, bls, ws);
  k_h<<<NP, 64, 0, stream>>>(x, ws, hi_g, fbn);
  k_pre<<<NP/4, 128, 0, stream>>>(W1, Wx1, bx1, ws);
  k_filter<<<256, 512, 0, stream>>>(ws, hi_g, cand, cnt_g, CAP);
  k_refine<<<NP/4, 256, 0, stream>>>(ws, cand, cnt_g, fbn, fbq, CAP);
  k_fb<<<256, 256, 0, stream>>>(ws, fbn, fbq);
  k_mlp<<<NP, 64, 0, stream>>>(b1, W2, Wx2, bx2, x, out, ws);
}

// Round 6
// 800.327 us; speedup vs baseline: 2.0272x; 1.2437x over previous
//
#include <hip/hip_runtime.h>

#define Bz 8
#define Nn 2048
#define Cc 128
#define KK 16
#define WD 512
#define F2 64
#define FO 128
#define NP (Bz*Nn)
#define SQ2 1.41421356237309515f
#define HSTRIDE 136   // padded bf16 row stride (16B-aligned)
#define CAPMAX 256

// ws layout (float offsets)
#define GOFF   ((size_t)0)
#define BEOFF  ((size_t)1024)
#define LSOFF  ((size_t)2048)
#define HOFF   ((size_t)3072)
#define SQOFF  (HOFF + (size_t)NP*Cc)
#define A1OFF  (SQOFF + (size_t)NP)
#define ADOFF  (A1OFF + (size_t)NP*F2)
#define HXOFF  (ADOFF + (size_t)NP*Cc)
#define IXOFF  (HXOFF + (size_t)NP*Cc)
#define CNTOFF (IXOFF + (size_t)NP*KK)
#define FBNOFF (CNTOFF + (size_t)NP)
#define FBQOFF (FBNOFF + (size_t)64)
// byte offsets for the u16 arrays
#define HIBYTES   ((FBQOFF + (size_t)NP) * 4)
#define W2TBYTES  (HIBYTES + (size_t)NP*HSTRIDE*2)     // bf16 W2^T  [128][64]
#define WX2TBYTES (W2TBYTES + (size_t)128*64*2)        // bf16 Wx2^T [128][128]
#define CANDBYTES (WX2TBYTES + (size_t)128*128*2)

typedef __attribute__((ext_vector_type(8))) short bf16x8;
typedef __attribute__((ext_vector_type(4))) float f32x4;

__device__ __forceinline__ unsigned short f2bf(float f) {
  unsigned u = __float_as_uint(f);
  unsigned r = (u + 0x7FFFu + ((u >> 16) & 1u)) >> 16;
  return (unsigned short)r;
}
__device__ __forceinline__ float lrelu(float v) {
  return (v > 0.f ? v : 0.2f*v) * SQ2;
}

// ---------------------------------------------------------------------------
// Kernel 1: per-batch FiLM vectors
__global__ __launch_bounds__(512) void k_pervec(const float* __restrict__ w,
    const float* __restrict__ Wg, const float* __restrict__ Wb,
    const float* __restrict__ Wls, const float* __restrict__ bls,
    float* __restrict__ ws) {
  __shared__ float red[3][4][Cc];
  const int b = blockIdx.x;
  const int c = threadIdx.x & 127, dc = threadIdx.x >> 7;
  const float* wr = w + b*WD;
  float ag = 0.f, ab = 0.f, al = 0.f;
  for (int d = dc*128; d < dc*128 + 128; ++d) {
    float wv = wr[d];
    ag = fmaf(wv, Wg[d*Cc + c], ag);
    ab = fmaf(wv, Wb[d*Cc + c], ab);
    al = fmaf(wv, Wls[d*Cc + c], al);
  }
  red[0][dc][c] = ag; red[1][dc][c] = ab; red[2][dc][c] = al;
  __syncthreads();
  if (dc == 0) {
    float sg = red[0][0][c] + red[0][1][c] + red[0][2][c] + red[0][3][c];
    float sb = red[1][0][c] + red[1][1][c] + red[1][2][c] + red[1][3][c];
    float sl = red[2][0][c] + red[2][1][c] + red[2][2][c] + red[2][3][c];
    ws[GOFF  + b*Cc + c] = 1.0f + sg;
    ws[BEOFF + b*Cc + c] = sb;
    ws[LSOFF + b*Cc + c] = sl + bls[c];
  }
}

// ---------------------------------------------------------------------------
// Kernel 1b: bf16-transposed weight copies for the MFMA MLP.
__global__ __launch_bounds__(256) void k_wprep(const float* __restrict__ W2,
    const float* __restrict__ Wx2, unsigned short* __restrict__ w2t,
    unsigned short* __restrict__ wx2t) {
  int idx = blockIdx.x*256 + threadIdx.x;
  if (idx < 128*64)  { int c = idx >> 6, j = idx & 63;  w2t[idx]  = f2bf(W2[j*FO + c]); }
  if (idx < 128*128) { int c = idx >> 7, j = idx & 127; wx2t[idx] = f2bf(Wx2[j*FO + c]); }
}

// ---------------------------------------------------------------------------
// Kernel 2: h = LN(x)*g + beta, sq = sum(h*h), hi = bf16(h); zero fb queue.
__global__ __launch_bounds__(64) void k_h(const float* __restrict__ x,
                                          float* __restrict__ ws,
                                          unsigned short* __restrict__ hi_g,
                                          int* __restrict__ fbn) {
  const int n = blockIdx.x;
  const int b = n >> 11;
  const int t = threadIdx.x;
  if (n == 0 && t == 0) fbn[0] = 0;
  const float* xr = x + (size_t)n*Cc;
  float x0 = xr[t], x1 = xr[t + 64];
  float s = x0 + x1, ss = x0*x0 + x1*x1;
  #pragma unroll
  for (int m = 1; m < 64; m <<= 1) {
    s  += __shfl_xor(s,  m, 64);
    ss += __shfl_xor(ss, m, 64);
  }
  float mu  = s * (1.0f/128.0f);
  float var = ss * (1.0f/128.0f) - mu*mu;
  float rs  = rsqrtf(var + 1e-5f);
  float h0 = (x0 - mu)*rs*ws[GOFF + b*Cc + t]      + ws[BEOFF + b*Cc + t];
  float h1 = (x1 - mu)*rs*ws[GOFF + b*Cc + t + 64] + ws[BEOFF + b*Cc + t + 64];
  float* hr = ws + HOFF + (size_t)n*Cc;
  hr[t] = h0; hr[t + 64] = h1;
  hi_g[(size_t)n*HSTRIDE + t]      = f2bf(h0);
  hi_g[(size_t)n*HSTRIDE + t + 64] = f2bf(h1);
  float q = h0*h0 + h1*h1;
  #pragma unroll
  for (int m = 1; m < 64; m <<= 1) q += __shfl_xor(q, m, 64);
  if (t == 0) ws[SQOFF + n] = q;
}

// ---------------------------------------------------------------------------
// Kernel 3: precompute A1 = h@W1, Ad = h@Wx1[128:], hxb = h@Wx1[:128]-Ad+bx1
__global__ __launch_bounds__(128) void k_pre(const float* __restrict__ W1,
    const float* __restrict__ Wx1, const float* __restrict__ bx1,
    float* __restrict__ ws) {
  __shared__ float hs[4][Cc];
  const int t = threadIdx.x;
  const size_t row0 = (size_t)blockIdx.x * 4;
  const float* h = ws + HOFF;
  #pragma unroll
  for (int r = 0; r < 4; ++r) hs[r][t] = h[(row0 + r)*Cc + t];
  __syncthreads();
  float ad[4] = {0,0,0,0}, ac[4] = {0,0,0,0};
  for (int cp = 0; cp < Cc; ++cp) {
    float whi = Wx1[cp*FO + t];
    float wlo = Wx1[(Cc + cp)*FO + t];
    #pragma unroll
    for (int r = 0; r < 4; ++r) {
      float hv = hs[r][cp];
      ac[r] = fmaf(hv, whi, ac[r]);
      ad[r] = fmaf(hv, wlo, ad[r]);
    }
  }
  float bx = bx1[t];
  #pragma unroll
  for (int r = 0; r < 4; ++r) {
    ws[ADOFF + (row0 + r)*Cc + t] = ad[r];
    ws[HXOFF + (row0 + r)*Cc + t] = ac[r] - ad[r] + bx;
  }
  const int j = t & 63, rp = t >> 6;
  float a0 = 0.f, a1 = 0.f;
  for (int cp = 0; cp < Cc; ++cp) {
    float wv = W1[cp*F2 + j];
    a0 = fmaf(hs[rp][cp],     wv, a0);
    a1 = fmaf(hs[rp + 2][cp], wv, a1);
  }
  ws[A1OFF + (row0 + rp)*F2 + j]     = a0;
  ws[A1OFF + (row0 + rp + 2)*F2 + j] = a1;
}

// ---------------------------------------------------------------------------
// Kernel 4: MFMA approx distances + tau-filter compaction.
// tau = 20th smallest of j-tiles {0..3} (512 samples) => cnt >= 19 guaranteed,
// E[cnt] ~ 80, P(cnt > 256) ~ 0.
__global__ __launch_bounds__(512, 1) void k_filter(float* __restrict__ ws,
    const unsigned short* __restrict__ hi_g, unsigned short* __restrict__ cand,
    int* __restrict__ cnt_g, int CAP) {
  __shared__ unsigned short hiA[64*HSTRIDE];   // 17408 B
  __shared__ float smB[8704];                  // hB u16[128*136] / dstage f32[64*132]
  __shared__ float t20[64][4][20];             // 20480 B
  __shared__ float sqA[64], sqB[128], tauS[64];
  __shared__ int cnt[64];
  unsigned short* hB = (unsigned short*)smB;
  float* dstage = smB;                         // stride 132
  const int t = threadIdx.x;
  const int b = blockIdx.x >> 5;
  const int i0 = (blockIdx.x & 31) << 6;
  const int wave = t >> 6, lane = t & 63;
  const int wi = wave & 1, wj = wave >> 1;
  const int l15 = lane & 15, l4 = lane >> 4;
  const float* __restrict__ sq = ws + SQOFF + (size_t)b*Nn;
  const unsigned short* __restrict__ hib = hi_g + (size_t)b*Nn*HSTRIDE;

  { // load hiA: 64 rows x 128 cols
    int r = t >> 3, o = (t & 7) * 16;
    *(bf16x8*)&hiA[r*HSTRIDE + o]     = *(const bf16x8*)&hib[(size_t)(i0 + r)*HSTRIDE + o];
    *(bf16x8*)&hiA[r*HSTRIDE + o + 8] = *(const bf16x8*)&hib[(size_t)(i0 + r)*HSTRIDE + o + 8];
  }
  if (t < 64) { sqA[t] = sq[i0 + t]; cnt[t] = 0; }

  // ---- tau pre-pass over j-tiles 0..3 ----
  for (int jt = 0; jt < 4; ++jt) {
    const int j0 = jt << 7;
    __syncthreads();
    { int r = t >> 2, o = (t & 3) * 32;
      #pragma unroll
      for (int q = 0; q < 4; ++q)
        *(bf16x8*)&hB[r*HSTRIDE + o + q*8] =
            *(const bf16x8*)&hib[(size_t)(j0 + r)*HSTRIDE + o + q*8];
    }
    if (t < 128) sqB[t] = sq[j0 + t];
    __syncthreads();
    f32x4 acc00 = {0,0,0,0}, acc01 = {0,0,0,0}, acc10 = {0,0,0,0}, acc11 = {0,0,0,0};
    #pragma unroll
    for (int kb = 0; kb < 4; ++kb) {
      const int cbase = kb*32 + l4*8;
      bf16x8 a0 = *(const bf16x8*)&hiA[(32*wi      + l15)*HSTRIDE + cbase];
      bf16x8 a1 = *(const bf16x8*)&hiA[(32*wi + 16 + l15)*HSTRIDE + cbase];
      bf16x8 b0 = *(const bf16x8*)&hB [(32*wj      + l15)*HSTRIDE + cbase];
      bf16x8 b1 = *(const bf16x8*)&hB [(32*wj + 16 + l15)*HSTRIDE + cbase];
      acc00 = __builtin_amdgcn_mfma_f32_16x16x32_bf16(a0, b0, acc00, 0, 0, 0);
      acc01 = __builtin_amdgcn_mfma_f32_16x16x32_bf16(a0, b1, acc01, 0, 0, 0);
      acc10 = __builtin_amdgcn_mfma_f32_16x16x32_bf16(a1, b0, acc10, 0, 0, 0);
      acc11 = __builtin_amdgcn_mfma_f32_16x16x32_bf16(a1, b1, acc11, 0, 0, 0);
    }
    __syncthreads();   // hB reads done -> reuse smB as dstage
    #pragma unroll
    for (int ib = 0; ib < 2; ++ib)
      #pragma unroll
      for (int jb = 0; jb < 2; ++jb) {
        const f32x4 a = ib ? (jb ? acc11 : acc10) : (jb ? acc01 : acc00);
        #pragma unroll
        for (int r = 0; r < 4; ++r) {
          int il = 32*wi + 16*ib + l4*4 + r;
          int jl = 32*wj + 16*jb + l15;
          dstage[il*132 + jl] = sqA[il] + sqB[jl] - 2.f*a[r];
        }
      }
    __syncthreads();
    { // per row: 20 smallest (ascending) of this tile's 128
      int row = wave*8;
      for (int rr = 0; rr < 8; ++rr, ++row) {
        float v0 = dstage[row*132 + lane];
        float v1 = dstage[row*132 + 64 + lane];
        #pragma unroll 1
        for (int r6 = 0; r6 < 20; ++r6) {
          float mv; int mi;
          if (v0 <= v1) { mv = v0; mi = lane; } else { mv = v1; mi = 64 + lane; }
          #pragma unroll
          for (int s2 = 1; s2 < 64; s2 <<= 1) {
            float ov = __shfl_xor(mv, s2, 64);
            int   oi = __shfl_xor(mi, s2, 64);
            if (ov < mv || (ov == mv && oi < mi)) { mv = ov; mi = oi; }
          }
          if (lane == 0) t20[row][jt][r6] = mv;
          if (mi == lane)      v0 = 3.0e38f;
          if (mi == 64 + lane) v1 = 3.0e38f;
        }
      }
    }
  }
  __syncthreads();
  if (t < 64) {  // 4-way merge of ascending 20-lists -> 20th smallest of 512
    int p0 = 0, p1 = 0, p2 = 0, p3 = 0; float tv = 0.f;
    #pragma unroll 1
    for (int s = 0; s < 20; ++s) {
      float v0 = (p0 < 20) ? t20[t][0][p0] : 3.0e38f;
      float v1 = (p1 < 20) ? t20[t][1][p1] : 3.0e38f;
      float v2 = (p2 < 20) ? t20[t][2][p2] : 3.0e38f;
      float v3 = (p3 < 20) ? t20[t][3][p3] : 3.0e38f;
      float m01 = fminf(v0, v1), m23 = fminf(v2, v3);
      tv = fminf(m01, m23);
      if (tv == v0)      ++p0;
      else if (tv == v1) ++p1;
      else if (tv == v2) ++p2;
      else               ++p3;
    }
    tauS[t] = tv;
  }

  // ---- main pass: all 16 j-tiles, filter from regs ----
  for (int jt = 0; jt < 16; ++jt) {
    const int j0 = jt << 7;
    __syncthreads();
    { int r = t >> 2, o = (t & 3) * 32;
      #pragma unroll
      for (int q = 0; q < 4; ++q)
        *(bf16x8*)&hB[r*HSTRIDE + o + q*8] =
            *(const bf16x8*)&hib[(size_t)(j0 + r)*HSTRIDE + o + q*8];
    }
    if (t < 128) sqB[t] = sq[j0 + t];
    __syncthreads();
    f32x4 acc00 = {0,0,0,0}, acc01 = {0,0,0,0}, acc10 = {0,0,0,0}, acc11 = {0,0,0,0};
    #pragma unroll
    for (int kb = 0; kb < 4; ++kb) {
      const int cbase = kb*32 + l4*8;
      bf16x8 a0 = *(const bf16x8*)&hiA[(32*wi      + l15)*HSTRIDE + cbase];
      bf16x8 a1 = *(const bf16x8*)&hiA[(32*wi + 16 + l15)*HSTRIDE + cbase];
      bf16x8 b0 = *(const bf16x8*)&hB [(32*wj      + l15)*HSTRIDE + cbase];
      bf16x8 b1 = *(const bf16x8*)&hB [(32*wj + 16 + l15)*HSTRIDE + cbase];
      acc00 = __builtin_amdgcn_mfma_f32_16x16x32_bf16(a0, b0, acc00, 0, 0, 0);
      acc01 = __builtin_amdgcn_mfma_f32_16x16x32_bf16(a0, b1, acc01, 0, 0, 0);
      acc10 = __builtin_amdgcn_mfma_f32_16x16x32_bf16(a1, b0, acc10, 0, 0, 0);
      acc11 = __builtin_amdgcn_mfma_f32_16x16x32_bf16(a1, b1, acc11, 0, 0, 0);
    }
    #pragma unroll
    for (int ib = 0; ib < 2; ++ib)
      #pragma unroll
      for (int jb = 0; jb < 2; ++jb) {
        const f32x4 a = ib ? (jb ? acc11 : acc10) : (jb ? acc01 : acc00);
        #pragma unroll
        for (int r = 0; r < 4; ++r) {
          int il = 32*wi + 16*ib + l4*4 + r;
          int jl = 32*wj + 16*jb + l15;
          float dv = sqA[il] + sqB[jl] - 2.f*a[r];
          if (dv < tauS[il]) {
            int pos = atomicAdd(&cnt[il], 1);
            if (pos < CAP)
              cand[(size_t)(b*Nn + i0 + il)*CAPMAX + pos] = (unsigned short)(j0 + jl);
          }
        }
      }
  }
  __syncthreads();
  if (t < 64) cnt_g[b*Nn + i0 + t] = cnt[t];
}

// ---------------------------------------------------------------------------
// Kernel 5: exact fp32 refine (8 lanes per candidate row) + fb-queue append.
__global__ __launch_bounds__(256) void k_refine(float* __restrict__ ws,
    const unsigned short* __restrict__ cand, const int* __restrict__ cnt_g,
    int* __restrict__ fbn, int* __restrict__ fbq, int CAP) {
  __shared__ float dsh[4][CAPMAX];
  __shared__ unsigned short cjs[4][CAPMAX];
  const int wave = threadIdx.x >> 6, lane = threadIdx.x & 63;
  const int s8 = lane >> 3, ch = lane & 7;
  const int row = blockIdx.x*4 + wave;
  const int b = row >> 11;
  const float* __restrict__ h = ws + HOFF;
  int c_ = cnt_g[row];
  int cm = (c_ < 17 || c_ > CAP) ? 0 : c_;
  if (cm == 0 && lane == 0) { int q = atomicAdd(fbn, 1); fbq[q] = row; }
  for (int cc = lane; cc < cm; cc += 64)
    cjs[wave][cc] = cand[(size_t)row*CAPMAX + cc];
  float4 hi4[4];
  #pragma unroll
  for (int q = 0; q < 4; ++q)
    hi4[q] = *(const float4*)&h[(size_t)row*Cc + ch*4 + q*32];
  __syncthreads();
  const int np8 = (cm + 7) >> 3;
  for (int p = 0; p < np8; ++p) {
    int slot = p*8 + s8;
    int sl = slot < cm ? slot : 0;
    int jj = cjs[wave][sl];
    const float* hj = h + (size_t)(b*Nn + jj)*Cc;
    float part = 0.f;
    #pragma unroll
    for (int q = 0; q < 4; ++q) {
      float4 v = *(const float4*)&hj[ch*4 + q*32];
      float e0 = hi4[q].x - v.x, e1 = hi4[q].y - v.y;
      float e2 = hi4[q].z - v.z, e3 = hi4[q].w - v.w;
      part = fmaf(e0, e0, part); part = fmaf(e1, e1, part);
      part = fmaf(e2, e2, part); part = fmaf(e3, e3, part);
    }
    part += __shfl_xor(part, 1, 64);
    part += __shfl_xor(part, 2, 64);
    part += __shfl_xor(part, 4, 64);
    if (ch == 0 && slot < cm) dsh[wave][slot] = part;
  }
  __syncthreads();
  int* op = (int*)(ws + IXOFF) + (size_t)row*KK;
  for (int cc = lane; cc < cm; cc += 64) {
    float dc = dsh[wave][cc];
    int jc = cjs[wave][cc];
    int rank = 0;
    #pragma unroll 1
    for (int m = 0; m < cm; ++m) {
      float dm = dsh[wave][m];
      int jm = cjs[wave][m];
      rank += (dm < dc || (dm == dc && jm < jc)) ? 1 : 0;
    }
    if (rank >= 1 && rank <= 16) op[rank - 1] = b*Nn + jc;
  }
}

// ---------------------------------------------------------------------------
// Kernel 6: fallback — queue-driven (expected empty), clamped for safety.
__global__ __launch_bounds__(256) void k_fb(float* __restrict__ ws,
    const int* __restrict__ fbn, const int* __restrict__ fbq) {
  __shared__ float fd[4][17];
  __shared__ int   fj[4][17];
  __shared__ float his[128];
  const int wave = threadIdx.x >> 6, lane = threadIdx.x & 63;
  int nfb = fbn[0];
  nfb = (nfb < 0) ? 0 : ((nfb > NP) ? NP : nfb);
  for (int q = blockIdx.x; q < nfb; q += gridDim.x) {
    const int row = fbq[q];
    if ((unsigned)row >= (unsigned)NP) continue;   // block-uniform
    const int b = row >> 11;
    const float* __restrict__ h = ws + HOFF + (size_t)b*Nn*Cc;
    if (threadIdx.x < 128) his[threadIdx.x] = h[(size_t)(row & (Nn-1))*Cc + threadIdx.x];
    __syncthreads();
    const float hi0 = his[lane], hi1 = his[lane + 64];
    float td[17]; int tj[17];
    #pragma unroll
    for (int s = 0; s < 17; ++s) { td[s] = 3.0e38f; tj[s] = 0x7FFFFFFF; }
    float cmax = 3.0e38f; int cjm = 0x7FFFFFFF, cpos = 0;
    const int jb = wave*512;
    #pragma unroll 1
    for (int it = 0; it < 256; ++it) {
      int j = jb + it*2;
      float a0 = h[(size_t)j*Cc + lane],     a1 = h[(size_t)j*Cc + lane + 64];
      float b0 = h[(size_t)(j+1)*Cc + lane], b1 = h[(size_t)(j+1)*Cc + lane + 64];
      float e0 = hi0 - a0, e1 = hi1 - a1, f0 = hi0 - b0, f1 = hi1 - b1;
      float p0 = e0*e0; p0 = fmaf(e1, e1, p0);
      float p1 = f0*f0; p1 = fmaf(f1, f1, p1);
      #pragma unroll
      for (int s2 = 1; s2 < 64; s2 <<= 1) {
        p0 += __shfl_xor(p0, s2, 64);
        p1 += __shfl_xor(p1, s2, 64);
      }
      #pragma unroll
      for (int u = 0; u < 2; ++u) {
        float d = u ? p1 : p0;
        int jd = j + u;
        if (d < cmax || (d == cmax && jd < cjm)) {
          #pragma unroll
          for (int s = 0; s < 17; ++s) {
            bool r = (s == cpos);
            td[s] = r ? d  : td[s];
            tj[s] = r ? jd : tj[s];
          }
          cmax = td[0]; cjm = tj[0]; cpos = 0;
          #pragma unroll
          for (int s = 1; s < 17; ++s)
            if (td[s] > cmax || (td[s] == cmax && tj[s] > cjm)) {
              cmax = td[s]; cjm = tj[s]; cpos = s;
            }
        }
      }
    }
    if (lane == 0) {
      #pragma unroll
      for (int s = 0; s < 17; ++s) { fd[wave][s] = td[s]; fj[wave][s] = tj[s]; }
    }
    __syncthreads();
    if (threadIdx.x < 68) {
      int e = threadIdx.x;
      float dc = fd[e / 17][e % 17];
      int   jc = fj[e / 17][e % 17];
      int rank = 0;
      #pragma unroll 1
      for (int m = 0; m < 68; ++m) {
        float dm = fd[m / 17][m % 17];
        int jm = fj[m / 17][m % 17];
        rank += (dm < dc || (dm == dc && jm < jc)) ? 1 : 0;
      }
      if (rank >= 1 && rank <= 16) {
        int* op = (int*)(ws + IXOFF) + (size_t)row*KK;
        op[rank - 1] = b*Nn + jc;
      }
    }
    __syncthreads();
  }
}

// ---------------------------------------------------------------------------
// Kernel 7: MFMA per-point MLP + softmax + aggregate + residual.
// One wave per point. hw: A-frag M=16(k-slot) K=64; hx: A-frag M=16 K=128.
// Weights: pre-transposed bf16 W2T[c][j], Wx2T[c][j] read straight from L2.
// C layout: col=lane&15 (channel within n-tile), row=(lane>>4)*4+r (k-slot).
// Softmax/aggregate over k-slots: in-reg over r + shfl_xor(16,32).
__global__ __launch_bounds__(256) void k_mlp(
    const float* __restrict__ b1v, const float* __restrict__ bx2,
    const unsigned short* __restrict__ w2t, const unsigned short* __restrict__ wx2t,
    const float* __restrict__ x, float* __restrict__ out,
    float* __restrict__ ws) {
  const int wave = threadIdx.x >> 6, lane = threadIdx.x & 63;
  const int n = blockIdx.x*4 + wave;
  const int b = n >> 11;
  const int l15 = lane & 15, l4 = lane >> 4;
  const int* __restrict__ ip = (const int*)(ws + IXOFF) + (size_t)n*KK;
  const int mk = ip[l15];                    // global row of neighbor slot l15

  // --- hw A-fragments (2 k-chunks over j=64) ---
  const float* __restrict__ A1 = ws + A1OFF;
  const float* a1m = A1 + (size_t)mk*F2;
  const float* a1n = A1 + (size_t)n*F2;
  bf16x8 hwA[2];
  #pragma unroll
  for (int c = 0; c < 2; ++c) {
    int off = c*32 + l4*8;
    float4 p0 = *(const float4*)(a1m + off), p1 = *(const float4*)(a1m + off + 4);
    float4 q0 = *(const float4*)(a1n + off), q1 = *(const float4*)(a1n + off + 4);
    float4 b0 = *(const float4*)(b1v + off), b1_ = *(const float4*)(b1v + off + 4);
    bf16x8 r;
    r[0] = (short)f2bf(lrelu(p0.x - q0.x + b0.x));
    r[1] = (short)f2bf(lrelu(p0.y - q0.y + b0.y));
    r[2] = (short)f2bf(lrelu(p0.z - q0.z + b0.z));
    r[3] = (short)f2bf(lrelu(p0.w - q0.w + b0.w));
    r[4] = (short)f2bf(lrelu(p1.x - q1.x + b1_.x));
    r[5] = (short)f2bf(lrelu(p1.y - q1.y + b1_.y));
    r[6] = (short)f2bf(lrelu(p1.z - q1.z + b1_.z));
    r[7] = (short)f2bf(lrelu(p1.w - q1.w + b1_.w));
    hwA[c] = r;
  }

  // --- wlog = hw @ W2 -> softmax over k-slots -> wsm (kept in wl[]) ---
  f32x4 wl[8];
  #pragma unroll
  for (int nt = 0; nt < 8; ++nt) {
    f32x4 acc = {0,0,0,0};
    acc = __builtin_amdgcn_mfma_f32_16x16x32_bf16(hwA[0],
            *(const bf16x8*)&w2t[(size_t)(nt*16 + l15)*64 + l4*8], acc, 0, 0, 0);
    acc = __builtin_amdgcn_mfma_f32_16x16x32_bf16(hwA[1],
            *(const bf16x8*)&w2t[(size_t)(nt*16 + l15)*64 + 32 + l4*8], acc, 0, 0, 0);
    wl[nt] = acc;
  }
  #pragma unroll
  for (int nt = 0; nt < 8; ++nt) {
    float mx = fmaxf(fmaxf(wl[nt][0], wl[nt][1]), fmaxf(wl[nt][2], wl[nt][3]));
    mx = fmaxf(mx, __shfl_xor(mx, 16, 64));
    mx = fmaxf(mx, __shfl_xor(mx, 32, 64));
    float e0 = __expf(wl[nt][0] - mx), e1 = __expf(wl[nt][1] - mx);
    float e2 = __expf(wl[nt][2] - mx), e3 = __expf(wl[nt][3] - mx);
    float sm = e0 + e1 + e2 + e3;
    sm += __shfl_xor(sm, 16, 64);
    sm += __shfl_xor(sm, 32, 64);
    float rs = 1.0f / sm;
    wl[nt][0] = e0*rs; wl[nt][1] = e1*rs; wl[nt][2] = e2*rs; wl[nt][3] = e3*rs;
  }

  // --- hx A-fragments (4 k-chunks over c=128) ---
  const float* adm = ws + ADOFF + (size_t)mk*Cc;
  const float* hxb = ws + HXOFF + (size_t)n*Cc;
  bf16x8 hxA[4];
  #pragma unroll
  for (int c = 0; c < 4; ++c) {
    int off = c*32 + l4*8;
    float4 p0 = *(const float4*)(adm + off), p1 = *(const float4*)(adm + off + 4);
    float4 q0 = *(const float4*)(hxb + off), q1 = *(const float4*)(hxb + off + 4);
    bf16x8 r;
    r[0] = (short)f2bf(lrelu(p0.x + q0.x));
    r[1] = (short)f2bf(lrelu(p0.y + q0.y));
    r[2] = (short)f2bf(lrelu(p0.z + q0.z));
    r[3] = (short)f2bf(lrelu(p0.w + q0.w));
    r[4] = (short)f2bf(lrelu(p1.x + q1.x));
    r[5] = (short)f2bf(lrelu(p1.y + q1.y));
    r[6] = (short)f2bf(lrelu(p1.z + q1.z));
    r[7] = (short)f2bf(lrelu(p1.w + q1.w));
    hxA[c] = r;
  }

  // --- xe = hx @ Wx2; agg = sum_k wsm*(xe+bx2); out = agg*ls + x ---
  #pragma unroll
  for (int nt = 0; nt < 8; ++nt) {
    f32x4 acc = {0,0,0,0};
    #pragma unroll
    for (int c = 0; c < 4; ++c)
      acc = __builtin_amdgcn_mfma_f32_16x16x32_bf16(hxA[c],
              *(const bf16x8*)&wx2t[(size_t)(nt*16 + l15)*128 + c*32 + l4*8],
              acc, 0, 0, 0);
    int col = nt*16 + l15;
    float bx = bx2[col];
    float ap = wl[nt][0]*(acc[0] + bx) + wl[nt][1]*(acc[1] + bx)
             + wl[nt][2]*(acc[2] + bx) + wl[nt][3]*(acc[3] + bx);
    ap += __shfl_xor(ap, 16, 64);
    ap += __shfl_xor(ap, 32, 64);
    if (l4 == 0) {
      size_t xo = (size_t)n*Cc + col;
      out[xo] = fmaf(ap, ws[LSOFF + b*Cc + col], x[xo]);
    }
  }
}

// ---------------------------------------------------------------------------
extern "C" void kernel_launch(void* const* d_in, const int* in_sizes, int n_in,
                              void* d_out, int out_size, void* d_ws, size_t ws_size,
                              hipStream_t stream) {
  const float* x   = (const float*)d_in[0];
  const float* w   = (const float*)d_in[1];
  const float* Wg  = (const float*)d_in[2];
  const float* Wb  = (const float*)d_in[3];
  const float* W1  = (const float*)d_in[4];
  const float* b1  = (const float*)d_in[5];
  const float* W2  = (const float*)d_in[6];
  const float* Wx1 = (const float*)d_in[8];
  const float* bx1 = (const float*)d_in[9];
  const float* Wx2 = (const float*)d_in[10];
  const float* bx2 = (const float*)d_in[11];
  const float* Wls = (const float*)d_in[12];
  const float* bls = (const float*)d_in[13];
  float* out = (float*)d_out;
  float* ws  = (float*)d_ws;
  unsigned short* hi_g = (unsigned short*)((char*)d_ws + HIBYTES);
  unsigned short* w2t  = (unsigned short*)((char*)d_ws + W2TBYTES);
  unsigned short* wx2t = (unsigned short*)((char*)d_ws + WX2TBYTES);
  unsigned short* cand = (unsigned short*)((char*)d_ws + CANDBYTES);
  int* cnt_g = (int*)(ws + CNTOFF);
  int* fbn   = (int*)(ws + FBNOFF);
  int* fbq   = (int*)(ws + FBQOFF);

  int CAP = 0;
  if (ws_size > CANDBYTES) {
    size_t c = (ws_size - CANDBYTES) / ((size_t)NP * 2);
    CAP = (c >= CAPMAX) ? CAPMAX : (int)c;
  }

  k_pervec<<<Bz, 512, 0, stream>>>(w, Wg, Wb, Wls, bls, ws);
  k_wprep<<<64, 256, 0, stream>>>(W2, Wx2, w2t, wx2t);
  k_h<<<NP, 64, 0, stream>>>(x, ws, hi_g, fbn);
  k_pre<<<NP/4, 128, 0, stream>>>(W1, Wx1, bx1, ws);
  k_filter<<<256, 512, 0, stream>>>(ws, hi_g, cand, cnt_g, CAP);
  k_refine<<<NP/4, 256, 0, stream>>>(ws, cand, cnt_g, fbn, fbq, CAP);
  k_fb<<<256, 256, 0, stream>>>(ws, fbn, fbq);
  k_mlp<<<NP/4, 256, 0, stream>>>(b1, bx2, w2t, wx2t, x, out, ws);
}

// Round 7
// 442.741 us; speedup vs baseline: 3.6645x; 1.8077x over previous
//
#include <hip/hip_runtime.h>

#define Bz 8
#define Nn 2048
#define Cc 128
#define KK 16
#define WD 512
#define F2 64
#define FO 128
#define NP (Bz*Nn)
#define SQ2 1.41421356237309515f
#define HSTRIDE 136   // padded bf16 row stride (16B-aligned)
#define CAPMAX 256

// ws layout (float offsets)
#define GOFF   ((size_t)0)
#define BEOFF  ((size_t)1024)
#define LSOFF  ((size_t)2048)
#define HOFF   ((size_t)3072)
#define SQOFF  (HOFF + (size_t)NP*Cc)
#define A1OFF  (SQOFF + (size_t)NP)
#define ADOFF  (A1OFF + (size_t)NP*F2)
#define HXOFF  (ADOFF + (size_t)NP*Cc)
#define IXOFF  (HXOFF + (size_t)NP*Cc)
#define CNTOFF (IXOFF + (size_t)NP*KK)
#define FBNOFF (CNTOFF + (size_t)NP)
#define FBQOFF (FBNOFF + (size_t)64)
// byte offsets for the u16 arrays
#define HIBYTES   ((FBQOFF + (size_t)NP) * 4)
#define W2TBYTES  (HIBYTES + (size_t)NP*HSTRIDE*2)     // bf16 W2^T  [128][64]
#define WX2TBYTES (W2TBYTES + (size_t)128*64*2)        // bf16 Wx2^T [128][128]
#define CANDBYTES (WX2TBYTES + (size_t)128*128*2)

typedef __attribute__((ext_vector_type(8))) short bf16x8;
typedef __attribute__((ext_vector_type(4))) float f32x4;

__device__ __forceinline__ unsigned short f2bf(float f) {
  unsigned u = __float_as_uint(f);
  unsigned r = (u + 0x7FFFu + ((u >> 16) & 1u)) >> 16;
  return (unsigned short)r;
}
__device__ __forceinline__ float lrelu(float v) {
  return (v > 0.f ? v : 0.2f*v) * SQ2;
}

// ---------------------------------------------------------------------------
// Kernel 1: per-batch FiLM vectors
__global__ __launch_bounds__(512) void k_pervec(const float* __restrict__ w,
    const float* __restrict__ Wg, const float* __restrict__ Wb,
    const float* __restrict__ Wls, const float* __restrict__ bls,
    float* __restrict__ ws) {
  __shared__ float red[3][4][Cc];
  const int b = blockIdx.x;
  const int c = threadIdx.x & 127, dc = threadIdx.x >> 7;
  const float* wr = w + b*WD;
  float ag = 0.f, ab = 0.f, al = 0.f;
  for (int d = dc*128; d < dc*128 + 128; ++d) {
    float wv = wr[d];
    ag = fmaf(wv, Wg[d*Cc + c], ag);
    ab = fmaf(wv, Wb[d*Cc + c], ab);
    al = fmaf(wv, Wls[d*Cc + c], al);
  }
  red[0][dc][c] = ag; red[1][dc][c] = ab; red[2][dc][c] = al;
  __syncthreads();
  if (dc == 0) {
    float sg = red[0][0][c] + red[0][1][c] + red[0][2][c] + red[0][3][c];
    float sb = red[1][0][c] + red[1][1][c] + red[1][2][c] + red[1][3][c];
    float sl = red[2][0][c] + red[2][1][c] + red[2][2][c] + red[2][3][c];
    ws[GOFF  + b*Cc + c] = 1.0f + sg;
    ws[BEOFF + b*Cc + c] = sb;
    ws[LSOFF + b*Cc + c] = sl + bls[c];
  }
}

// ---------------------------------------------------------------------------
// Kernel 1b: bf16-transposed weight copies for the MFMA MLP.
__global__ __launch_bounds__(256) void k_wprep(const float* __restrict__ W2,
    const float* __restrict__ Wx2, unsigned short* __restrict__ w2t,
    unsigned short* __restrict__ wx2t) {
  int idx = blockIdx.x*256 + threadIdx.x;
  if (idx < 128*64)  { int c = idx >> 6, j = idx & 63;  w2t[idx]  = f2bf(W2[j*FO + c]); }
  if (idx < 128*128) { int c = idx >> 7, j = idx & 127; wx2t[idx] = f2bf(Wx2[j*FO + c]); }
}

// ---------------------------------------------------------------------------
// Kernel 2: h = LN(x)*g + beta, sq = sum(h*h), hi = bf16(h); zero fb queue.
__global__ __launch_bounds__(64) void k_h(const float* __restrict__ x,
                                          float* __restrict__ ws,
                                          unsigned short* __restrict__ hi_g,
                                          int* __restrict__ fbn) {
  const int n = blockIdx.x;
  const int b = n >> 11;
  const int t = threadIdx.x;
  if (n == 0 && t == 0) fbn[0] = 0;
  const float* xr = x + (size_t)n*Cc;
  float x0 = xr[t], x1 = xr[t + 64];
  float s = x0 + x1, ss = x0*x0 + x1*x1;
  #pragma unroll
  for (int m = 1; m < 64; m <<= 1) {
    s  += __shfl_xor(s,  m, 64);
    ss += __shfl_xor(ss, m, 64);
  }
  float mu  = s * (1.0f/128.0f);
  float var = ss * (1.0f/128.0f) - mu*mu;
  float rs  = rsqrtf(var + 1e-5f);
  float h0 = (x0 - mu)*rs*ws[GOFF + b*Cc + t]      + ws[BEOFF + b*Cc + t];
  float h1 = (x1 - mu)*rs*ws[GOFF + b*Cc + t + 64] + ws[BEOFF + b*Cc + t + 64];
  float* hr = ws + HOFF + (size_t)n*Cc;
  hr[t] = h0; hr[t + 64] = h1;
  hi_g[(size_t)n*HSTRIDE + t]      = f2bf(h0);
  hi_g[(size_t)n*HSTRIDE + t + 64] = f2bf(h1);
  float q = h0*h0 + h1*h1;
  #pragma unroll
  for (int m = 1; m < 64; m <<= 1) q += __shfl_xor(q, m, 64);
  if (t == 0) ws[SQOFF + n] = q;
}

// ---------------------------------------------------------------------------
// Kernel 3: precompute A1 = h@W1, Ad = h@Wx1[128:], hxb = h@Wx1[:128]-Ad+bx1
__global__ __launch_bounds__(128) void k_pre(const float* __restrict__ W1,
    const float* __restrict__ Wx1, const float* __restrict__ bx1,
    float* __restrict__ ws) {
  __shared__ float hs[4][Cc];
  const int t = threadIdx.x;
  const size_t row0 = (size_t)blockIdx.x * 4;
  const float* h = ws + HOFF;
  #pragma unroll
  for (int r = 0; r < 4; ++r) hs[r][t] = h[(row0 + r)*Cc + t];
  __syncthreads();
  float ad[4] = {0,0,0,0}, ac[4] = {0,0,0,0};
  for (int cp = 0; cp < Cc; ++cp) {
    float whi = Wx1[cp*FO + t];
    float wlo = Wx1[(Cc + cp)*FO + t];
    #pragma unroll
    for (int r = 0; r < 4; ++r) {
      float hv = hs[r][cp];
      ac[r] = fmaf(hv, whi, ac[r]);
      ad[r] = fmaf(hv, wlo, ad[r]);
    }
  }
  float bx = bx1[t];
  #pragma unroll
  for (int r = 0; r < 4; ++r) {
    ws[ADOFF + (row0 + r)*Cc + t] = ad[r];
    ws[HXOFF + (row0 + r)*Cc + t] = ac[r] - ad[r] + bx;
  }
  const int j = t & 63, rp = t >> 6;
  float a0 = 0.f, a1 = 0.f;
  for (int cp = 0; cp < Cc; ++cp) {
    float wv = W1[cp*F2 + j];
    a0 = fmaf(hs[rp][cp],     wv, a0);
    a1 = fmaf(hs[rp + 2][cp], wv, a1);
  }
  ws[A1OFF + (row0 + rp)*F2 + j]     = a0;
  ws[A1OFF + (row0 + rp + 2)*F2 + j] = a1;
}

// ---------------------------------------------------------------------------
// Kernel 4: MFMA approx distances + tau-filter compaction.
// 32-row i-tiles, grid 512 (2 blocks/CU), 512 thr.
// Prepass tiles 0..3: distances kept in regs (samp[4][8]); tau per row by
// 18-iter count-bisection (target: >=20 sample values < tau => cnt >= 19).
// Tiles 0..3 filtered from regs; main pass covers tiles 4..15.
__global__ __launch_bounds__(512, 4) void k_filter(float* __restrict__ ws,
    const unsigned short* __restrict__ hi_g, unsigned short* __restrict__ cand,
    int* __restrict__ cnt_g, int CAP) {
  __shared__ unsigned short hiA[32*HSTRIDE];   // 8704 B
  __shared__ float smB[8704];                  // hB u16[128*136] / dstage f32[32*132]
  __shared__ float sqA[32], sqB[128], tauS[32];
  __shared__ int cnt[32];
  unsigned short* hB = (unsigned short*)smB;
  float* dstage = smB;                         // stride 132
  const int t = threadIdx.x;
  const int b  = blockIdx.x >> 6;
  const int i0 = (blockIdx.x & 63) << 5;
  const int wave = t >> 6, lane = t & 63;
  const int wi = wave & 1, wj = wave >> 1;     // 16-row group, 32-col group
  const int l15 = lane & 15, l4 = lane >> 4;
  const float* __restrict__ sq = ws + SQOFF + (size_t)b*Nn;
  const unsigned short* __restrict__ hib = hi_g + (size_t)b*Nn*HSTRIDE;

  { // load hiA: 32 rows x 128 cols
    int r = t >> 4, o = (t & 15) * 8;
    *(bf16x8*)&hiA[r*HSTRIDE + o] = *(const bf16x8*)&hib[(size_t)(i0 + r)*HSTRIDE + o];
  }
  if (t < 32) { sqA[t] = sq[i0 + t]; cnt[t] = 0; }

  float samp[4][8];   // [row r][tile*2 + half]; row = wave*4 + r, col = half*64+lane

  // ---- prepass: tiles 0..3 -> dstage -> sample regs ----
  for (int jt = 0; jt < 4; ++jt) {
    const int j0 = jt << 7;
    __syncthreads();                       // dstage reads / prev hB reads done
    { int r = t >> 2, o = (t & 3) * 32;
      #pragma unroll
      for (int q = 0; q < 4; ++q)
        *(bf16x8*)&hB[r*HSTRIDE + o + q*8] =
            *(const bf16x8*)&hib[(size_t)(j0 + r)*HSTRIDE + o + q*8];
    }
    if (t < 128) sqB[t] = sq[j0 + t];
    __syncthreads();
    f32x4 acc0 = {0,0,0,0}, acc1 = {0,0,0,0};
    #pragma unroll
    for (int kb = 0; kb < 4; ++kb) {
      const int cbase = kb*32 + l4*8;
      bf16x8 a  = *(const bf16x8*)&hiA[(16*wi + l15)*HSTRIDE + cbase];
      bf16x8 b0 = *(const bf16x8*)&hB [(32*wj      + l15)*HSTRIDE + cbase];
      bf16x8 b1 = *(const bf16x8*)&hB [(32*wj + 16 + l15)*HSTRIDE + cbase];
      acc0 = __builtin_amdgcn_mfma_f32_16x16x32_bf16(a, b0, acc0, 0, 0, 0);
      acc1 = __builtin_amdgcn_mfma_f32_16x16x32_bf16(a, b1, acc1, 0, 0, 0);
    }
    __syncthreads();                       // hB reads done -> write dstage
    #pragma unroll
    for (int jb = 0; jb < 2; ++jb) {
      const f32x4 a = jb ? acc1 : acc0;
      #pragma unroll
      for (int r = 0; r < 4; ++r) {
        int il = 16*wi + l4*4 + r;
        int jl = 32*wj + 16*jb + l15;
        dstage[il*132 + jl] = sqA[il] + sqB[jl] - 2.f*a[r];
      }
    }
    __syncthreads();
    #pragma unroll
    for (int r = 0; r < 4; ++r) {
      int row = wave*4 + r;
      samp[r][jt*2]     = dstage[row*132 + lane];
      samp[r][jt*2 + 1] = dstage[row*132 + 64 + lane];
    }
  }

  // ---- tau by bisection (4 rows interleaved for ILP) ----
  {
    float lo[4], hi[4];
    #pragma unroll
    for (int r = 0; r < 4; ++r) {
      float m = samp[r][0];
      #pragma unroll
      for (int k = 1; k < 8; ++k) m = fmaxf(m, samp[r][k]);
      #pragma unroll
      for (int s2 = 1; s2 < 64; s2 <<= 1) m = fmaxf(m, __shfl_xor(m, s2, 64));
      hi[r] = fmaxf(m, 0.f)*1.0001f + 1e-6f;
      lo[r] = 0.f;
    }
    #pragma unroll 1
    for (int it = 0; it < 18; ++it) {
      float mid[4], cv[4];
      #pragma unroll
      for (int r = 0; r < 4; ++r) {
        mid[r] = 0.5f*(lo[r] + hi[r]);
        float c = 0.f;
        #pragma unroll
        for (int k = 0; k < 8; ++k) c += (samp[r][k] < mid[r]) ? 1.f : 0.f;
        cv[r] = c;
      }
      #pragma unroll
      for (int s2 = 1; s2 < 64; s2 <<= 1) {
        #pragma unroll
        for (int r = 0; r < 4; ++r) cv[r] += __shfl_xor(cv[r], s2, 64);
      }
      #pragma unroll
      for (int r = 0; r < 4; ++r) {
        bool ge = cv[r] >= 20.f;
        hi[r] = ge ? mid[r] : hi[r];
        lo[r] = ge ? lo[r] : mid[r];
      }
    }
    if (lane == 0) {
      #pragma unroll
      for (int r = 0; r < 4; ++r) tauS[wave*4 + r] = hi[r];
    }
    __syncthreads();
    // filter tiles 0..3 straight from the sample regs
    #pragma unroll
    for (int r = 0; r < 4; ++r) {
      int row = wave*4 + r;
      float tv = hi[r];
      size_t rg = (size_t)(b*Nn + i0 + row);
      #pragma unroll
      for (int k = 0; k < 8; ++k) {
        if (samp[r][k] < tv) {
          int j = (k >> 1)*128 + (k & 1)*64 + lane;
          int pos = atomicAdd(&cnt[row], 1);
          if (pos < CAP) cand[rg*CAPMAX + pos] = (unsigned short)j;
        }
      }
    }
  }

  // ---- main pass: tiles 4..15, filter from acc regs ----
  for (int jt = 4; jt < 16; ++jt) {
    const int j0 = jt << 7;
    __syncthreads();                       // prev filter's sqB/hB reads done
    { int r = t >> 2, o = (t & 3) * 32;
      #pragma unroll
      for (int q = 0; q < 4; ++q)
        *(bf16x8*)&hB[r*HSTRIDE + o + q*8] =
            *(const bf16x8*)&hib[(size_t)(j0 + r)*HSTRIDE + o + q*8];
    }
    if (t < 128) sqB[t] = sq[j0 + t];
    __syncthreads();
    f32x4 acc0 = {0,0,0,0}, acc1 = {0,0,0,0};
    #pragma unroll
    for (int kb = 0; kb < 4; ++kb) {
      const int cbase = kb*32 + l4*8;
      bf16x8 a  = *(const bf16x8*)&hiA[(16*wi + l15)*HSTRIDE + cbase];
      bf16x8 b0 = *(const bf16x8*)&hB [(32*wj      + l15)*HSTRIDE + cbase];
      bf16x8 b1 = *(const bf16x8*)&hB [(32*wj + 16 + l15)*HSTRIDE + cbase];
      acc0 = __builtin_amdgcn_mfma_f32_16x16x32_bf16(a, b0, acc0, 0, 0, 0);
      acc1 = __builtin_amdgcn_mfma_f32_16x16x32_bf16(a, b1, acc1, 0, 0, 0);
    }
    #pragma unroll
    for (int jb = 0; jb < 2; ++jb) {
      const f32x4 a = jb ? acc1 : acc0;
      #pragma unroll
      for (int r = 0; r < 4; ++r) {
        int il = 16*wi + l4*4 + r;
        int jl = 32*wj + 16*jb + l15;
        float dv = sqA[il] + sqB[jl] - 2.f*a[r];
        if (dv < tauS[il]) {
          int pos = atomicAdd(&cnt[il], 1);
          if (pos < CAP)
            cand[(size_t)(b*Nn + i0 + il)*CAPMAX + pos] = (unsigned short)(j0 + jl);
        }
      }
    }
  }
  __syncthreads();
  if (t < 32) cnt_g[b*Nn + i0 + t] = cnt[t];
}

// ---------------------------------------------------------------------------
// Kernel 5: exact fp32 refine (8 lanes per candidate row) + fb-queue append.
__global__ __launch_bounds__(256) void k_refine(float* __restrict__ ws,
    const unsigned short* __restrict__ cand, const int* __restrict__ cnt_g,
    int* __restrict__ fbn, int* __restrict__ fbq, int CAP) {
  __shared__ float dsh[4][CAPMAX];
  __shared__ unsigned short cjs[4][CAPMAX];
  const int wave = threadIdx.x >> 6, lane = threadIdx.x & 63;
  const int s8 = lane >> 3, ch = lane & 7;
  const int row = blockIdx.x*4 + wave;
  const int b = row >> 11;
  const float* __restrict__ h = ws + HOFF;
  int c_ = cnt_g[row];
  int cm = (c_ < 17 || c_ > CAP) ? 0 : c_;
  if (cm == 0 && lane == 0) { int q = atomicAdd(fbn, 1); fbq[q] = row; }
  for (int cc = lane; cc < cm; cc += 64)
    cjs[wave][cc] = cand[(size_t)row*CAPMAX + cc];
  float4 hi4[4];
  #pragma unroll
  for (int q = 0; q < 4; ++q)
    hi4[q] = *(const float4*)&h[(size_t)row*Cc + ch*4 + q*32];
  __syncthreads();
  const int np8 = (cm + 7) >> 3;
  for (int p = 0; p < np8; ++p) {
    int slot = p*8 + s8;
    int sl = slot < cm ? slot : 0;
    int jj = cjs[wave][sl];
    const float* hj = h + (size_t)(b*Nn + jj)*Cc;
    float part = 0.f;
    #pragma unroll
    for (int q = 0; q < 4; ++q) {
      float4 v = *(const float4*)&hj[ch*4 + q*32];
      float e0 = hi4[q].x - v.x, e1 = hi4[q].y - v.y;
      float e2 = hi4[q].z - v.z, e3 = hi4[q].w - v.w;
      part = fmaf(e0, e0, part); part = fmaf(e1, e1, part);
      part = fmaf(e2, e2, part); part = fmaf(e3, e3, part);
    }
    part += __shfl_xor(part, 1, 64);
    part += __shfl_xor(part, 2, 64);
    part += __shfl_xor(part, 4, 64);
    if (ch == 0 && slot < cm) dsh[wave][slot] = part;
  }
  __syncthreads();
  int* op = (int*)(ws + IXOFF) + (size_t)row*KK;
  for (int cc = lane; cc < cm; cc += 64) {
    float dc = dsh[wave][cc];
    int jc = cjs[wave][cc];
    int rank = 0;
    #pragma unroll 1
    for (int m = 0; m < cm; ++m) {
      float dm = dsh[wave][m];
      int jm = cjs[wave][m];
      rank += (dm < dc || (dm == dc && jm < jc)) ? 1 : 0;
    }
    if (rank >= 1 && rank <= 16) op[rank - 1] = b*Nn + jc;
  }
}

// ---------------------------------------------------------------------------
// Kernel 6: fallback — queue-driven (expected empty), clamped for safety.
__global__ __launch_bounds__(256) void k_fb(float* __restrict__ ws,
    const int* __restrict__ fbn, const int* __restrict__ fbq) {
  __shared__ float fd[4][17];
  __shared__ int   fj[4][17];
  __shared__ float his[128];
  const int wave = threadIdx.x >> 6, lane = threadIdx.x & 63;
  int nfb = fbn[0];
  nfb = (nfb < 0) ? 0 : ((nfb > NP) ? NP : nfb);
  for (int q = blockIdx.x; q < nfb; q += gridDim.x) {
    const int row = fbq[q];
    if ((unsigned)row >= (unsigned)NP) continue;   // block-uniform
    const int b = row >> 11;
    const float* __restrict__ h = ws + HOFF + (size_t)b*Nn*Cc;
    if (threadIdx.x < 128) his[threadIdx.x] = h[(size_t)(row & (Nn-1))*Cc + threadIdx.x];
    __syncthreads();
    const float hi0 = his[lane], hi1 = his[lane + 64];
    float td[17]; int tj[17];
    #pragma unroll
    for (int s = 0; s < 17; ++s) { td[s] = 3.0e38f; tj[s] = 0x7FFFFFFF; }
    float cmax = 3.0e38f; int cjm = 0x7FFFFFFF, cpos = 0;
    const int jb = wave*512;
    #pragma unroll 1
    for (int it = 0; it < 256; ++it) {
      int j = jb + it*2;
      float a0 = h[(size_t)j*Cc + lane],     a1 = h[(size_t)j*Cc + lane + 64];
      float b0 = h[(size_t)(j+1)*Cc + lane], b1 = h[(size_t)(j+1)*Cc + lane + 64];
      float e0 = hi0 - a0, e1 = hi1 - a1, f0 = hi0 - b0, f1 = hi1 - b1;
      float p0 = e0*e0; p0 = fmaf(e1, e1, p0);
      float p1 = f0*f0; p1 = fmaf(f1, f1, p1);
      #pragma unroll
      for (int s2 = 1; s2 < 64; s2 <<= 1) {
        p0 += __shfl_xor(p0, s2, 64);
        p1 += __shfl_xor(p1, s2, 64);
      }
      #pragma unroll
      for (int u = 0; u < 2; ++u) {
        float d = u ? p1 : p0;
        int jd = j + u;
        if (d < cmax || (d == cmax && jd < cjm)) {
          #pragma unroll
          for (int s = 0; s < 17; ++s) {
            bool r = (s == cpos);
            td[s] = r ? d  : td[s];
            tj[s] = r ? jd : tj[s];
          }
          cmax = td[0]; cjm = tj[0]; cpos = 0;
          #pragma unroll
          for (int s = 1; s < 17; ++s)
            if (td[s] > cmax || (td[s] == cmax && tj[s] > cjm)) {
              cmax = td[s]; cjm = tj[s]; cpos = s;
            }
        }
      }
    }
    if (lane == 0) {
      #pragma unroll
      for (int s = 0; s < 17; ++s) { fd[wave][s] = td[s]; fj[wave][s] = tj[s]; }
    }
    __syncthreads();
    if (threadIdx.x < 68) {
      int e = threadIdx.x;
      float dc = fd[e / 17][e % 17];
      int   jc = fj[e / 17][e % 17];
      int rank = 0;
      #pragma unroll 1
      for (int m = 0; m < 68; ++m) {
        float dm = fd[m / 17][m % 17];
        int jm = fj[m / 17][m % 17];
        rank += (dm < dc || (dm == dc && jm < jc)) ? 1 : 0;
      }
      if (rank >= 1 && rank <= 16) {
        int* op = (int*)(ws + IXOFF) + (size_t)row*KK;
        op[rank - 1] = b*Nn + jc;
      }
    }
    __syncthreads();
  }
}

// ---------------------------------------------------------------------------
// Kernel 7: MFMA per-point MLP + softmax + aggregate + residual.
__global__ __launch_bounds__(256) void k_mlp(
    const float* __restrict__ b1v, const float* __restrict__ bx2,
    const unsigned short* __restrict__ w2t, const unsigned short* __restrict__ wx2t,
    const float* __restrict__ x, float* __restrict__ out,
    float* __restrict__ ws) {
  const int wave = threadIdx.x >> 6, lane = threadIdx.x & 63;
  const int n = blockIdx.x*4 + wave;
  const int b = n >> 11;
  const int l15 = lane & 15, l4 = lane >> 4;
  const int* __restrict__ ip = (const int*)(ws + IXOFF) + (size_t)n*KK;
  const int mk = ip[l15];

  const float* __restrict__ A1 = ws + A1OFF;
  const float* a1m = A1 + (size_t)mk*F2;
  const float* a1n = A1 + (size_t)n*F2;
  bf16x8 hwA[2];
  #pragma unroll
  for (int c = 0; c < 2; ++c) {
    int off = c*32 + l4*8;
    float4 p0 = *(const float4*)(a1m + off), p1 = *(const float4*)(a1m + off + 4);
    float4 q0 = *(const float4*)(a1n + off), q1 = *(const float4*)(a1n + off + 4);
    float4 b0 = *(const float4*)(b1v + off), b1_ = *(const float4*)(b1v + off + 4);
    bf16x8 r;
    r[0] = (short)f2bf(lrelu(p0.x - q0.x + b0.x));
    r[1] = (short)f2bf(lrelu(p0.y - q0.y + b0.y));
    r[2] = (short)f2bf(lrelu(p0.z - q0.z + b0.z));
    r[3] = (short)f2bf(lrelu(p0.w - q0.w + b0.w));
    r[4] = (short)f2bf(lrelu(p1.x - q1.x + b1_.x));
    r[5] = (short)f2bf(lrelu(p1.y - q1.y + b1_.y));
    r[6] = (short)f2bf(lrelu(p1.z - q1.z + b1_.z));
    r[7] = (short)f2bf(lrelu(p1.w - q1.w + b1_.w));
    hwA[c] = r;
  }

  f32x4 wl[8];
  #pragma unroll
  for (int nt = 0; nt < 8; ++nt) {
    f32x4 acc = {0,0,0,0};
    acc = __builtin_amdgcn_mfma_f32_16x16x32_bf16(hwA[0],
            *(const bf16x8*)&w2t[(size_t)(nt*16 + l15)*64 + l4*8], acc, 0, 0, 0);
    acc = __builtin_amdgcn_mfma_f32_16x16x32_bf16(hwA[1],
            *(const bf16x8*)&w2t[(size_t)(nt*16 + l15)*64 + 32 + l4*8], acc, 0, 0, 0);
    wl[nt] = acc;
  }
  #pragma unroll
  for (int nt = 0; nt < 8; ++nt) {
    float mx = fmaxf(fmaxf(wl[nt][0], wl[nt][1]), fmaxf(wl[nt][2], wl[nt][3]));
    mx = fmaxf(mx, __shfl_xor(mx, 16, 64));
    mx = fmaxf(mx, __shfl_xor(mx, 32, 64));
    float e0 = __expf(wl[nt][0] - mx), e1 = __expf(wl[nt][1] - mx);
    float e2 = __expf(wl[nt][2] - mx), e3 = __expf(wl[nt][3] - mx);
    float sm = e0 + e1 + e2 + e3;
    sm += __shfl_xor(sm, 16, 64);
    sm += __shfl_xor(sm, 32, 64);
    float rs = 1.0f / sm;
    wl[nt][0] = e0*rs; wl[nt][1] = e1*rs; wl[nt][2] = e2*rs; wl[nt][3] = e3*rs;
  }

  const float* adm = ws + ADOFF + (size_t)mk*Cc;
  const float* hxb = ws + HXOFF + (size_t)n*Cc;
  bf16x8 hxA[4];
  #pragma unroll
  for (int c = 0; c < 4; ++c) {
    int off = c*32 + l4*8;
    float4 p0 = *(const float4*)(adm + off), p1 = *(const float4*)(adm + off + 4);
    float4 q0 = *(const float4*)(hxb + off), q1 = *(const float4*)(hxb + off + 4);
    bf16x8 r;
    r[0] = (short)f2bf(lrelu(p0.x + q0.x));
    r[1] = (short)f2bf(lrelu(p0.y + q0.y));
    r[2] = (short)f2bf(lrelu(p0.z + q0.z));
    r[3] = (short)f2bf(lrelu(p0.w + q0.w));
    r[4] = (short)f2bf(lrelu(p1.x + q1.x));
    r[5] = (short)f2bf(lrelu(p1.y + q1.y));
    r[6] = (short)f2bf(lrelu(p1.z + q1.z));
    r[7] = (short)f2bf(lrelu(p1.w + q1.w));
    hxA[c] = r;
  }

  #pragma unroll
  for (int nt = 0; nt < 8; ++nt) {
    f32x4 acc = {0,0,0,0};
    #pragma unroll
    for (int c = 0; c < 4; ++c)
      acc = __builtin_amdgcn_mfma_f32_16x16x32_bf16(hxA[c],
              *(const bf16x8*)&wx2t[(size_t)(nt*16 + l15)*128 + c*32 + l4*8],
              acc, 0, 0, 0);
    int col = nt*16 + l15;
    float bx = bx2[col];
    float ap = wl[nt][0]*(acc[0] + bx) + wl[nt][1]*(acc[1] + bx)
             + wl[nt][2]*(acc[2] + bx) + wl[nt][3]*(acc[3] + bx);
    ap += __shfl_xor(ap, 16, 64);
    ap += __shfl_xor(ap, 32, 64);
    if (l4 == 0) {
      size_t xo = (size_t)n*Cc + col;
      out[xo] = fmaf(ap, ws[LSOFF + b*Cc + col], x[xo]);
    }
  }
}

// ---------------------------------------------------------------------------
extern "C" void kernel_launch(void* const* d_in, const int* in_sizes, int n_in,
                              void* d_out, int out_size, void* d_ws, size_t ws_size,
                              hipStream_t stream) {
  const float* x   = (const float*)d_in[0];
  const float* w   = (const float*)d_in[1];
  const float* Wg  = (const float*)d_in[2];
  const float* Wb  = (const float*)d_in[3];
  const float* W1  = (const float*)d_in[4];
  const float* b1  = (const float*)d_in[5];
  const float* W2  = (const float*)d_in[6];
  const float* Wx1 = (const float*)d_in[8];
  const float* bx1 = (const float*)d_in[9];
  const float* Wx2 = (const float*)d_in[10];
  const float* bx2 = (const float*)d_in[11];
  const float* Wls = (const float*)d_in[12];
  const float* bls = (const float*)d_in[13];
  float* out = (float*)d_out;
  float* ws  = (float*)d_ws;
  unsigned short* hi_g = (unsigned short*)((char*)d_ws + HIBYTES);
  unsigned short* w2t  = (unsigned short*)((char*)d_ws + W2TBYTES);
  unsigned short* wx2t = (unsigned short*)((char*)d_ws + WX2TBYTES);
  unsigned short* cand = (unsigned short*)((char*)d_ws + CANDBYTES);
  int* cnt_g = (int*)(ws + CNTOFF);
  int* fbn   = (int*)(ws + FBNOFF);
  int* fbq   = (int*)(ws + FBQOFF);

  int CAP = 0;
  if (ws_size > CANDBYTES) {
    size_t c = (ws_size - CANDBYTES) / ((size_t)NP * 2);
    CAP = (c >= CAPMAX) ? CAPMAX : (int)c;
  }

  k_pervec<<<Bz, 512, 0, stream>>>(w, Wg, Wb, Wls, bls, ws);
  k_wprep<<<64, 256, 0, stream>>>(W2, Wx2, w2t, wx2t);
  k_h<<<NP, 64, 0, stream>>>(x, ws, hi_g, fbn);
  k_pre<<<NP/4, 128, 0, stream>>>(W1, Wx1, bx1, ws);
  k_filter<<<512, 512, 0, stream>>>(ws, hi_g, cand, cnt_g, CAP);
  k_refine<<<NP/4, 256, 0, stream>>>(ws, cand, cnt_g, fbn, fbq, CAP);
  k_fb<<<256, 256, 0, stream>>>(ws, fbn, fbq);
  k_mlp<<<NP/4, 256, 0, stream>>>(b1, bx2, w2t, wx2t, x, out, ws);
}

// Round 8
// 438.104 us; speedup vs baseline: 3.7033x; 1.0106x over previous
//
#include <hip/hip_runtime.h>

#define Bz 8
#define Nn 2048
#define Cc 128
#define KK 16
#define WD 512
#define F2 64
#define FO 128
#define NP (Bz*Nn)
#define SQ2 1.41421356237309515f
#define HSTRIDE 136   // padded bf16 row stride (16B-aligned)
#define CAPMAX 256

// ws layout (float offsets)
#define GOFF   ((size_t)0)
#define BEOFF  ((size_t)1024)
#define LSOFF  ((size_t)2048)
#define HOFF   ((size_t)3072)
#define SQOFF  (HOFF + (size_t)NP*Cc)
#define A1OFF  (SQOFF + (size_t)NP)
#define ADOFF  (A1OFF + (size_t)NP*F2)
#define HXOFF  (ADOFF + (size_t)NP*Cc)
#define IXOFF  (HXOFF + (size_t)NP*Cc)
#define CNTOFF (IXOFF + (size_t)NP*KK)
#define FBNOFF (CNTOFF + (size_t)NP)
#define FBQOFF (FBNOFF + (size_t)64)
// byte offsets for the u16 arrays
#define HIBYTES   ((FBQOFF + (size_t)NP) * 4)
#define W2TBYTES  (HIBYTES + (size_t)NP*HSTRIDE*2)     // bf16 W2^T  [128][64]
#define WX2TBYTES (W2TBYTES + (size_t)128*64*2)        // bf16 Wx2^T [128][128]
#define CANDBYTES (WX2TBYTES + (size_t)128*128*2)

typedef __attribute__((ext_vector_type(8))) short bf16x8;
typedef __attribute__((ext_vector_type(4))) float f32x4;

__device__ __forceinline__ unsigned short f2bf(float f) {
  unsigned u = __float_as_uint(f);
  unsigned r = (u + 0x7FFFu + ((u >> 16) & 1u)) >> 16;
  return (unsigned short)r;
}
__device__ __forceinline__ float lrelu(float v) {
  return (v > 0.f ? v : 0.2f*v) * SQ2;
}

// ---------------------------------------------------------------------------
// Kernel 1: per-batch FiLM vectors
__global__ __launch_bounds__(512) void k_pervec(const float* __restrict__ w,
    const float* __restrict__ Wg, const float* __restrict__ Wb,
    const float* __restrict__ Wls, const float* __restrict__ bls,
    float* __restrict__ ws) {
  __shared__ float red[3][4][Cc];
  const int b = blockIdx.x;
  const int c = threadIdx.x & 127, dc = threadIdx.x >> 7;
  const float* wr = w + b*WD;
  float ag = 0.f, ab = 0.f, al = 0.f;
  for (int d = dc*128; d < dc*128 + 128; ++d) {
    float wv = wr[d];
    ag = fmaf(wv, Wg[d*Cc + c], ag);
    ab = fmaf(wv, Wb[d*Cc + c], ab);
    al = fmaf(wv, Wls[d*Cc + c], al);
  }
  red[0][dc][c] = ag; red[1][dc][c] = ab; red[2][dc][c] = al;
  __syncthreads();
  if (dc == 0) {
    float sg = red[0][0][c] + red[0][1][c] + red[0][2][c] + red[0][3][c];
    float sb = red[1][0][c] + red[1][1][c] + red[1][2][c] + red[1][3][c];
    float sl = red[2][0][c] + red[2][1][c] + red[2][2][c] + red[2][3][c];
    ws[GOFF  + b*Cc + c] = 1.0f + sg;
    ws[BEOFF + b*Cc + c] = sb;
    ws[LSOFF + b*Cc + c] = sl + bls[c];
  }
}

// ---------------------------------------------------------------------------
// Kernel 1b: bf16-transposed weight copies for the MFMA MLP.
__global__ __launch_bounds__(256) void k_wprep(const float* __restrict__ W2,
    const float* __restrict__ Wx2, unsigned short* __restrict__ w2t,
    unsigned short* __restrict__ wx2t) {
  int idx = blockIdx.x*256 + threadIdx.x;
  if (idx < 128*64)  { int c = idx >> 6, j = idx & 63;  w2t[idx]  = f2bf(W2[j*FO + c]); }
  if (idx < 128*128) { int c = idx >> 7, j = idx & 127; wx2t[idx] = f2bf(Wx2[j*FO + c]); }
}

// ---------------------------------------------------------------------------
// Kernel 2: h = LN(x)*g + beta, sq = sum(h*h), hi = bf16(h); zero fb queue.
__global__ __launch_bounds__(64) void k_h(const float* __restrict__ x,
                                          float* __restrict__ ws,
                                          unsigned short* __restrict__ hi_g,
                                          int* __restrict__ fbn) {
  const int n = blockIdx.x;
  const int b = n >> 11;
  const int t = threadIdx.x;
  if (n == 0 && t == 0) fbn[0] = 0;
  const float* xr = x + (size_t)n*Cc;
  float x0 = xr[t], x1 = xr[t + 64];
  float s = x0 + x1, ss = x0*x0 + x1*x1;
  #pragma unroll
  for (int m = 1; m < 64; m <<= 1) {
    s  += __shfl_xor(s,  m, 64);
    ss += __shfl_xor(ss, m, 64);
  }
  float mu  = s * (1.0f/128.0f);
  float var = ss * (1.0f/128.0f) - mu*mu;
  float rs  = rsqrtf(var + 1e-5f);
  float h0 = (x0 - mu)*rs*ws[GOFF + b*Cc + t]      + ws[BEOFF + b*Cc + t];
  float h1 = (x1 - mu)*rs*ws[GOFF + b*Cc + t + 64] + ws[BEOFF + b*Cc + t + 64];
  float* hr = ws + HOFF + (size_t)n*Cc;
  hr[t] = h0; hr[t + 64] = h1;
  hi_g[(size_t)n*HSTRIDE + t]      = f2bf(h0);
  hi_g[(size_t)n*HSTRIDE + t + 64] = f2bf(h1);
  float q = h0*h0 + h1*h1;
  #pragma unroll
  for (int m = 1; m < 64; m <<= 1) q += __shfl_xor(q, m, 64);
  if (t == 0) ws[SQOFF + n] = q;
}

// ---------------------------------------------------------------------------
// Kernel 3: precompute A1 = h@W1, Ad = h@Wx1[128:], hxb = h@Wx1[:128]-Ad+bx1
__global__ __launch_bounds__(128) void k_pre(const float* __restrict__ W1,
    const float* __restrict__ Wx1, const float* __restrict__ bx1,
    float* __restrict__ ws) {
  __shared__ float hs[4][Cc];
  const int t = threadIdx.x;
  const size_t row0 = (size_t)blockIdx.x * 4;
  const float* h = ws + HOFF;
  #pragma unroll
  for (int r = 0; r < 4; ++r) hs[r][t] = h[(row0 + r)*Cc + t];
  __syncthreads();
  float ad[4] = {0,0,0,0}, ac[4] = {0,0,0,0};
  for (int cp = 0; cp < Cc; ++cp) {
    float whi = Wx1[cp*FO + t];
    float wlo = Wx1[(Cc + cp)*FO + t];
    #pragma unroll
    for (int r = 0; r < 4; ++r) {
      float hv = hs[r][cp];
      ac[r] = fmaf(hv, whi, ac[r]);
      ad[r] = fmaf(hv, wlo, ad[r]);
    }
  }
  float bx = bx1[t];
  #pragma unroll
  for (int r = 0; r < 4; ++r) {
    ws[ADOFF + (row0 + r)*Cc + t] = ad[r];
    ws[HXOFF + (row0 + r)*Cc + t] = ac[r] - ad[r] + bx;
  }
  const int j = t & 63, rp = t >> 6;
  float a0 = 0.f, a1 = 0.f;
  for (int cp = 0; cp < Cc; ++cp) {
    float wv = W1[cp*F2 + j];
    a0 = fmaf(hs[rp][cp],     wv, a0);
    a1 = fmaf(hs[rp + 2][cp], wv, a1);
  }
  ws[A1OFF + (row0 + rp)*F2 + j]     = a0;
  ws[A1OFF + (row0 + rp + 2)*F2 + j] = a1;
}

// ---------------------------------------------------------------------------
// Kernel 4: MFMA approx distances + tau-filter compaction. (unchanged from r7)
__global__ __launch_bounds__(512, 4) void k_filter(float* __restrict__ ws,
    const unsigned short* __restrict__ hi_g, unsigned short* __restrict__ cand,
    int* __restrict__ cnt_g, int CAP) {
  __shared__ unsigned short hiA[32*HSTRIDE];   // 8704 B
  __shared__ float smB[8704];                  // hB u16[128*136] / dstage f32[32*132]
  __shared__ float sqA[32], sqB[128], tauS[32];
  __shared__ int cnt[32];
  unsigned short* hB = (unsigned short*)smB;
  float* dstage = smB;                         // stride 132
  const int t = threadIdx.x;
  const int b  = blockIdx.x >> 6;
  const int i0 = (blockIdx.x & 63) << 5;
  const int wave = t >> 6, lane = t & 63;
  const int wi = wave & 1, wj = wave >> 1;
  const int l15 = lane & 15, l4 = lane >> 4;
  const float* __restrict__ sq = ws + SQOFF + (size_t)b*Nn;
  const unsigned short* __restrict__ hib = hi_g + (size_t)b*Nn*HSTRIDE;

  { // load hiA: 32 rows x 128 cols
    int r = t >> 4, o = (t & 15) * 8;
    *(bf16x8*)&hiA[r*HSTRIDE + o] = *(const bf16x8*)&hib[(size_t)(i0 + r)*HSTRIDE + o];
  }
  if (t < 32) { sqA[t] = sq[i0 + t]; cnt[t] = 0; }

  float samp[4][8];

  // ---- prepass: tiles 0..3 -> dstage -> sample regs ----
  for (int jt = 0; jt < 4; ++jt) {
    const int j0 = jt << 7;
    __syncthreads();
    { int r = t >> 2, o = (t & 3) * 32;
      #pragma unroll
      for (int q = 0; q < 4; ++q)
        *(bf16x8*)&hB[r*HSTRIDE + o + q*8] =
            *(const bf16x8*)&hib[(size_t)(j0 + r)*HSTRIDE + o + q*8];
    }
    if (t < 128) sqB[t] = sq[j0 + t];
    __syncthreads();
    f32x4 acc0 = {0,0,0,0}, acc1 = {0,0,0,0};
    #pragma unroll
    for (int kb = 0; kb < 4; ++kb) {
      const int cbase = kb*32 + l4*8;
      bf16x8 a  = *(const bf16x8*)&hiA[(16*wi + l15)*HSTRIDE + cbase];
      bf16x8 b0 = *(const bf16x8*)&hB [(32*wj      + l15)*HSTRIDE + cbase];
      bf16x8 b1 = *(const bf16x8*)&hB [(32*wj + 16 + l15)*HSTRIDE + cbase];
      acc0 = __builtin_amdgcn_mfma_f32_16x16x32_bf16(a, b0, acc0, 0, 0, 0);
      acc1 = __builtin_amdgcn_mfma_f32_16x16x32_bf16(a, b1, acc1, 0, 0, 0);
    }
    __syncthreads();
    #pragma unroll
    for (int jb = 0; jb < 2; ++jb) {
      const f32x4 a = jb ? acc1 : acc0;
      #pragma unroll
      for (int r = 0; r < 4; ++r) {
        int il = 16*wi + l4*4 + r;
        int jl = 32*wj + 16*jb + l15;
        dstage[il*132 + jl] = sqA[il] + sqB[jl] - 2.f*a[r];
      }
    }
    __syncthreads();
    #pragma unroll
    for (int r = 0; r < 4; ++r) {
      int row = wave*4 + r;
      samp[r][jt*2]     = dstage[row*132 + lane];
      samp[r][jt*2 + 1] = dstage[row*132 + 64 + lane];
    }
  }

  // ---- tau by bisection ----
  {
    float lo[4], hi[4];
    #pragma unroll
    for (int r = 0; r < 4; ++r) {
      float m = samp[r][0];
      #pragma unroll
      for (int k = 1; k < 8; ++k) m = fmaxf(m, samp[r][k]);
      #pragma unroll
      for (int s2 = 1; s2 < 64; s2 <<= 1) m = fmaxf(m, __shfl_xor(m, s2, 64));
      hi[r] = fmaxf(m, 0.f)*1.0001f + 1e-6f;
      lo[r] = 0.f;
    }
    #pragma unroll 1
    for (int it = 0; it < 18; ++it) {
      float mid[4], cv[4];
      #pragma unroll
      for (int r = 0; r < 4; ++r) {
        mid[r] = 0.5f*(lo[r] + hi[r]);
        float c = 0.f;
        #pragma unroll
        for (int k = 0; k < 8; ++k) c += (samp[r][k] < mid[r]) ? 1.f : 0.f;
        cv[r] = c;
      }
      #pragma unroll
      for (int s2 = 1; s2 < 64; s2 <<= 1) {
        #pragma unroll
        for (int r = 0; r < 4; ++r) cv[r] += __shfl_xor(cv[r], s2, 64);
      }
      #pragma unroll
      for (int r = 0; r < 4; ++r) {
        bool ge = cv[r] >= 20.f;
        hi[r] = ge ? mid[r] : hi[r];
        lo[r] = ge ? lo[r] : mid[r];
      }
    }
    if (lane == 0) {
      #pragma unroll
      for (int r = 0; r < 4; ++r) tauS[wave*4 + r] = hi[r];
    }
    __syncthreads();
    #pragma unroll
    for (int r = 0; r < 4; ++r) {
      int row = wave*4 + r;
      float tv = hi[r];
      size_t rg = (size_t)(b*Nn + i0 + row);
      #pragma unroll
      for (int k = 0; k < 8; ++k) {
        if (samp[r][k] < tv) {
          int j = (k >> 1)*128 + (k & 1)*64 + lane;
          int pos = atomicAdd(&cnt[row], 1);
          if (pos < CAP) cand[rg*CAPMAX + pos] = (unsigned short)j;
        }
      }
    }
  }

  // ---- main pass: tiles 4..15 ----
  for (int jt = 4; jt < 16; ++jt) {
    const int j0 = jt << 7;
    __syncthreads();
    { int r = t >> 2, o = (t & 3) * 32;
      #pragma unroll
      for (int q = 0; q < 4; ++q)
        *(bf16x8*)&hB[r*HSTRIDE + o + q*8] =
            *(const bf16x8*)&hib[(size_t)(j0 + r)*HSTRIDE + o + q*8];
    }
    if (t < 128) sqB[t] = sq[j0 + t];
    __syncthreads();
    f32x4 acc0 = {0,0,0,0}, acc1 = {0,0,0,0};
    #pragma unroll
    for (int kb = 0; kb < 4; ++kb) {
      const int cbase = kb*32 + l4*8;
      bf16x8 a  = *(const bf16x8*)&hiA[(16*wi + l15)*HSTRIDE + cbase];
      bf16x8 b0 = *(const bf16x8*)&hB [(32*wj      + l15)*HSTRIDE + cbase];
      bf16x8 b1 = *(const bf16x8*)&hB [(32*wj + 16 + l15)*HSTRIDE + cbase];
      acc0 = __builtin_amdgcn_mfma_f32_16x16x32_bf16(a, b0, acc0, 0, 0, 0);
      acc1 = __builtin_amdgcn_mfma_f32_16x16x32_bf16(a, b1, acc1, 0, 0, 0);
    }
    #pragma unroll
    for (int jb = 0; jb < 2; ++jb) {
      const f32x4 a = jb ? acc1 : acc0;
      #pragma unroll
      for (int r = 0; r < 4; ++r) {
        int il = 16*wi + l4*4 + r;
        int jl = 32*wj + 16*jb + l15;
        float dv = sqA[il] + sqB[jl] - 2.f*a[r];
        if (dv < tauS[il]) {
          int pos = atomicAdd(&cnt[il], 1);
          if (pos < CAP)
            cand[(size_t)(b*Nn + i0 + il)*CAPMAX + pos] = (unsigned short)(j0 + jl);
        }
      }
    }
  }
  __syncthreads();
  if (t < 32) cnt_g[b*Nn + i0 + t] = cnt[t];
}

// ---------------------------------------------------------------------------
// Kernel 5: exact fp32 refine + fb-queue append. XCD-swizzled: blk&7 = batch.
__global__ __launch_bounds__(256) void k_refine(float* __restrict__ ws,
    const unsigned short* __restrict__ cand, const int* __restrict__ cnt_g,
    int* __restrict__ fbn, int* __restrict__ fbq, int CAP) {
  __shared__ float dsh[4][CAPMAX];
  __shared__ unsigned short cjs[4][CAPMAX];
  const int wave = threadIdx.x >> 6, lane = threadIdx.x & 63;
  const int s8 = lane >> 3, ch = lane & 7;
  const int blk = blockIdx.x;
  const int row = ((blk & 7)*512 + (blk >> 3))*4 + wave;   // batch = blk&7
  const int b = row >> 11;
  const float* __restrict__ h = ws + HOFF;
  int c_ = cnt_g[row];
  int cm = (c_ < 17 || c_ > CAP) ? 0 : c_;
  if (cm == 0 && lane == 0) { int q = atomicAdd(fbn, 1); fbq[q] = row; }
  for (int cc = lane; cc < cm; cc += 64)
    cjs[wave][cc] = cand[(size_t)row*CAPMAX + cc];
  float4 hi4[4];
  #pragma unroll
  for (int q = 0; q < 4; ++q)
    hi4[q] = *(const float4*)&h[(size_t)row*Cc + ch*4 + q*32];
  __syncthreads();
  const int np8 = (cm + 7) >> 3;
  for (int p = 0; p < np8; ++p) {
    int slot = p*8 + s8;
    int sl = slot < cm ? slot : 0;
    int jj = cjs[wave][sl];
    const float* hj = h + (size_t)(b*Nn + jj)*Cc;
    float part = 0.f;
    #pragma unroll
    for (int q = 0; q < 4; ++q) {
      float4 v = *(const float4*)&hj[ch*4 + q*32];
      float e0 = hi4[q].x - v.x, e1 = hi4[q].y - v.y;
      float e2 = hi4[q].z - v.z, e3 = hi4[q].w - v.w;
      part = fmaf(e0, e0, part); part = fmaf(e1, e1, part);
      part = fmaf(e2, e2, part); part = fmaf(e3, e3, part);
    }
    part += __shfl_xor(part, 1, 64);
    part += __shfl_xor(part, 2, 64);
    part += __shfl_xor(part, 4, 64);
    if (ch == 0 && slot < cm) dsh[wave][slot] = part;
  }
  __syncthreads();
  int* op = (int*)(ws + IXOFF) + (size_t)row*KK;
  for (int cc = lane; cc < cm; cc += 64) {
    float dc = dsh[wave][cc];
    int jc = cjs[wave][cc];
    int rank = 0;
    #pragma unroll 1
    for (int m = 0; m < cm; ++m) {
      float dm = dsh[wave][m];
      int jm = cjs[wave][m];
      rank += (dm < dc || (dm == dc && jm < jc)) ? 1 : 0;
    }
    if (rank >= 1 && rank <= 16) op[rank - 1] = b*Nn + jc;
  }
}

// ---------------------------------------------------------------------------
// Kernel 6: fallback — queue-driven (expected empty), clamped for safety.
__global__ __launch_bounds__(256) void k_fb(float* __restrict__ ws,
    const int* __restrict__ fbn, const int* __restrict__ fbq) {
  __shared__ float fd[4][17];
  __shared__ int   fj[4][17];
  __shared__ float his[128];
  const int wave = threadIdx.x >> 6, lane = threadIdx.x & 63;
  int nfb = fbn[0];
  nfb = (nfb < 0) ? 0 : ((nfb > NP) ? NP : nfb);
  for (int q = blockIdx.x; q < nfb; q += gridDim.x) {
    const int row = fbq[q];
    if ((unsigned)row >= (unsigned)NP) continue;
    const int b = row >> 11;
    const float* __restrict__ h = ws + HOFF + (size_t)b*Nn*Cc;
    if (threadIdx.x < 128) his[threadIdx.x] = h[(size_t)(row & (Nn-1))*Cc + threadIdx.x];
    __syncthreads();
    const float hi0 = his[lane], hi1 = his[lane + 64];
    float td[17]; int tj[17];
    #pragma unroll
    for (int s = 0; s < 17; ++s) { td[s] = 3.0e38f; tj[s] = 0x7FFFFFFF; }
    float cmax = 3.0e38f; int cjm = 0x7FFFFFFF, cpos = 0;
    const int jb = wave*512;
    #pragma unroll 1
    for (int it = 0; it < 256; ++it) {
      int j = jb + it*2;
      float a0 = h[(size_t)j*Cc + lane],     a1 = h[(size_t)j*Cc + lane + 64];
      float b0 = h[(size_t)(j+1)*Cc + lane], b1 = h[(size_t)(j+1)*Cc + lane + 64];
      float e0 = hi0 - a0, e1 = hi1 - a1, f0 = hi0 - b0, f1 = hi1 - b1;
      float p0 = e0*e0; p0 = fmaf(e1, e1, p0);
      float p1 = f0*f0; p1 = fmaf(f1, f1, p1);
      #pragma unroll
      for (int s2 = 1; s2 < 64; s2 <<= 1) {
        p0 += __shfl_xor(p0, s2, 64);
        p1 += __shfl_xor(p1, s2, 64);
      }
      #pragma unroll
      for (int u = 0; u < 2; ++u) {
        float d = u ? p1 : p0;
        int jd = j + u;
        if (d < cmax || (d == cmax && jd < cjm)) {
          #pragma unroll
          for (int s = 0; s < 17; ++s) {
            bool r = (s == cpos);
            td[s] = r ? d  : td[s];
            tj[s] = r ? jd : tj[s];
          }
          cmax = td[0]; cjm = tj[0]; cpos = 0;
          #pragma unroll
          for (int s = 1; s < 17; ++s)
            if (td[s] > cmax || (td[s] == cmax && tj[s] > cjm)) {
              cmax = td[s]; cjm = tj[s]; cpos = s;
            }
        }
      }
    }
    if (lane == 0) {
      #pragma unroll
      for (int s = 0; s < 17; ++s) { fd[wave][s] = td[s]; fj[wave][s] = tj[s]; }
    }
    __syncthreads();
    if (threadIdx.x < 68) {
      int e = threadIdx.x;
      float dc = fd[e / 17][e % 17];
      int   jc = fj[e / 17][e % 17];
      int rank = 0;
      #pragma unroll 1
      for (int m = 0; m < 68; ++m) {
        float dm = fd[m / 17][m % 17];
        int jm = fj[m / 17][m % 17];
        rank += (dm < dc || (dm == dc && jm < jc)) ? 1 : 0;
      }
      if (rank >= 1 && rank <= 16) {
        int* op = (int*)(ws + IXOFF) + (size_t)row*KK;
        op[rank - 1] = b*Nn + jc;
      }
    }
    __syncthreads();
  }
}

// ---------------------------------------------------------------------------
// Kernel 7: MFMA per-point MLP. XCD-swizzled (blk&7 = batch); all gathers
// (hwA + hxA) issued before the first MFMA so W2-GEMM+softmax VALU work
// overlaps the Ad-gather latency.
__global__ __launch_bounds__(256) void k_mlp(
    const float* __restrict__ b1v, const float* __restrict__ bx2,
    const unsigned short* __restrict__ w2t, const unsigned short* __restrict__ wx2t,
    const float* __restrict__ x, float* __restrict__ out,
    float* __restrict__ ws) {
  const int wave = threadIdx.x >> 6, lane = threadIdx.x & 63;
  const int blk = blockIdx.x;
  const int n = ((blk & 7)*512 + (blk >> 3))*4 + wave;     // batch = blk&7
  const int b = n >> 11;
  const int l15 = lane & 15, l4 = lane >> 4;
  const int* __restrict__ ip = (const int*)(ws + IXOFF) + (size_t)n*KK;
  const int mk = ip[l15];

  // --- gather phase: hwA and hxA fragments (independent of MFMA results) ---
  const float* __restrict__ A1 = ws + A1OFF;
  const float* a1m = A1 + (size_t)mk*F2;
  const float* a1n = A1 + (size_t)n*F2;
  bf16x8 hwA[2];
  #pragma unroll
  for (int c = 0; c < 2; ++c) {
    int off = c*32 + l4*8;
    float4 p0 = *(const float4*)(a1m + off), p1 = *(const float4*)(a1m + off + 4);
    float4 q0 = *(const float4*)(a1n + off), q1 = *(const float4*)(a1n + off + 4);
    float4 b0 = *(const float4*)(b1v + off), b1_ = *(const float4*)(b1v + off + 4);
    bf16x8 r;
    r[0] = (short)f2bf(lrelu(p0.x - q0.x + b0.x));
    r[1] = (short)f2bf(lrelu(p0.y - q0.y + b0.y));
    r[2] = (short)f2bf(lrelu(p0.z - q0.z + b0.z));
    r[3] = (short)f2bf(lrelu(p0.w - q0.w + b0.w));
    r[4] = (short)f2bf(lrelu(p1.x - q1.x + b1_.x));
    r[5] = (short)f2bf(lrelu(p1.y - q1.y + b1_.y));
    r[6] = (short)f2bf(lrelu(p1.z - q1.z + b1_.z));
    r[7] = (short)f2bf(lrelu(p1.w - q1.w + b1_.w));
    hwA[c] = r;
  }
  const float* adm = ws + ADOFF + (size_t)mk*Cc;
  const float* hxb = ws + HXOFF + (size_t)n*Cc;
  bf16x8 hxA[4];
  #pragma unroll
  for (int c = 0; c < 4; ++c) {
    int off = c*32 + l4*8;
    float4 p0 = *(const float4*)(adm + off), p1 = *(const float4*)(adm + off + 4);
    float4 q0 = *(const float4*)(hxb + off), q1 = *(const float4*)(hxb + off + 4);
    bf16x8 r;
    r[0] = (short)f2bf(lrelu(p0.x + q0.x));
    r[1] = (short)f2bf(lrelu(p0.y + q0.y));
    r[2] = (short)f2bf(lrelu(p0.z + q0.z));
    r[3] = (short)f2bf(lrelu(p0.w + q0.w));
    r[4] = (short)f2bf(lrelu(p1.x + q1.x));
    r[5] = (short)f2bf(lrelu(p1.y + q1.y));
    r[6] = (short)f2bf(lrelu(p1.z + q1.z));
    r[7] = (short)f2bf(lrelu(p1.w + q1.w));
    hxA[c] = r;
  }

  // --- wlog = hw @ W2 -> softmax over k-slots ---
  f32x4 wl[8];
  #pragma unroll
  for (int nt = 0; nt < 8; ++nt) {
    f32x4 acc = {0,0,0,0};
    acc = __builtin_amdgcn_mfma_f32_16x16x32_bf16(hwA[0],
            *(const bf16x8*)&w2t[(size_t)(nt*16 + l15)*64 + l4*8], acc, 0, 0, 0);
    acc = __builtin_amdgcn_mfma_f32_16x16x32_bf16(hwA[1],
            *(const bf16x8*)&w2t[(size_t)(nt*16 + l15)*64 + 32 + l4*8], acc, 0, 0, 0);
    wl[nt] = acc;
  }
  #pragma unroll
  for (int nt = 0; nt < 8; ++nt) {
    float mx = fmaxf(fmaxf(wl[nt][0], wl[nt][1]), fmaxf(wl[nt][2], wl[nt][3]));
    mx = fmaxf(mx, __shfl_xor(mx, 16, 64));
    mx = fmaxf(mx, __shfl_xor(mx, 32, 64));
    float e0 = __expf(wl[nt][0] - mx), e1 = __expf(wl[nt][1] - mx);
    float e2 = __expf(wl[nt][2] - mx), e3 = __expf(wl[nt][3] - mx);
    float sm = e0 + e1 + e2 + e3;
    sm += __shfl_xor(sm, 16, 64);
    sm += __shfl_xor(sm, 32, 64);
    float rs = 1.0f / sm;
    wl[nt][0] = e0*rs; wl[nt][1] = e1*rs; wl[nt][2] = e2*rs; wl[nt][3] = e3*rs;
  }

  // --- xe = hx @ Wx2; agg; out = agg*ls + x ---
  #pragma unroll
  for (int nt = 0; nt < 8; ++nt) {
    f32x4 acc = {0,0,0,0};
    #pragma unroll
    for (int c = 0; c < 4; ++c)
      acc = __builtin_amdgcn_mfma_f32_16x16x32_bf16(hxA[c],
              *(const bf16x8*)&wx2t[(size_t)(nt*16 + l15)*128 + c*32 + l4*8],
              acc, 0, 0, 0);
    int col = nt*16 + l15;
    float bx = bx2[col];
    float ap = wl[nt][0]*(acc[0] + bx) + wl[nt][1]*(acc[1] + bx)
             + wl[nt][2]*(acc[2] + bx) + wl[nt][3]*(acc[3] + bx);
    ap += __shfl_xor(ap, 16, 64);
    ap += __shfl_xor(ap, 32, 64);
    if (l4 == 0) {
      size_t xo = (size_t)n*Cc + col;
      out[xo] = fmaf(ap, ws[LSOFF + b*Cc + col], x[xo]);
    }
  }
}

// ---------------------------------------------------------------------------
extern "C" void kernel_launch(void* const* d_in, const int* in_sizes, int n_in,
                              void* d_out, int out_size, void* d_ws, size_t ws_size,
                              hipStream_t stream) {
  const float* x   = (const float*)d_in[0];
  const float* w   = (const float*)d_in[1];
  const float* Wg  = (const float*)d_in[2];
  const float* Wb  = (const float*)d_in[3];
  const float* W1  = (const float*)d_in[4];
  const float* b1  = (const float*)d_in[5];
  const float* W2  = (const float*)d_in[6];
  const float* Wx1 = (const float*)d_in[8];
  const float* bx1 = (const float*)d_in[9];
  const float* Wx2 = (const float*)d_in[10];
  const float* bx2 = (const float*)d_in[11];
  const float* Wls = (const float*)d_in[12];
  const float* bls = (const float*)d_in[13];
  float* out = (float*)d_out;
  float* ws  = (float*)d_ws;
  unsigned short* hi_g = (unsigned short*)((char*)d_ws + HIBYTES);
  unsigned short* w2t  = (unsigned short*)((char*)d_ws + W2TBYTES);
  unsigned short* wx2t = (unsigned short*)((char*)d_ws + WX2TBYTES);
  unsigned short* cand = (unsigned short*)((char*)d_ws + CANDBYTES);
  int* cnt_g = (int*)(ws + CNTOFF);
  int* fbn   = (int*)(ws + FBNOFF);
  int* fbq   = (int*)(ws + FBQOFF);

  int CAP = 0;
  if (ws_size > CANDBYTES) {
    size_t c = (ws_size - CANDBYTES) / ((size_t)NP * 2);
    CAP = (c >= CAPMAX) ? CAPMAX : (int)c;
  }

  k_pervec<<<Bz, 512, 0, stream>>>(w, Wg, Wb, Wls, bls, ws);
  k_wprep<<<64, 256, 0, stream>>>(W2, Wx2, w2t, wx2t);
  k_h<<<NP, 64, 0, stream>>>(x, ws, hi_g, fbn);
  k_pre<<<NP/4, 128, 0, stream>>>(W1, Wx1, bx1, ws);
  k_filter<<<512, 512, 0, stream>>>(ws, hi_g, cand, cnt_g, CAP);
  k_refine<<<NP/4, 256, 0, stream>>>(ws, cand, cnt_g, fbn, fbq, CAP);
  k_fb<<<256, 256, 0, stream>>>(ws, fbn, fbq);
  k_mlp<<<NP/4, 256, 0, stream>>>(b1, bx2, w2t, wx2t, x, out, ws);
}

// Round 9
// 419.484 us; speedup vs baseline: 3.8676x; 1.0444x over previous
//
#include <hip/hip_runtime.h>

#define Bz 8
#define Nn 2048
#define Cc 128
#define KK 16
#define WD 512
#define F2 64
#define FO 128
#define NP (Bz*Nn)
#define SQ2 1.41421356237309515f
#define HSTRIDE 136   // padded bf16 row stride (16B-aligned)
#define CAPMAX 256

// ws layout (float offsets)
#define GOFF   ((size_t)0)
#define BEOFF  ((size_t)1024)
#define LSOFF  ((size_t)2048)
#define HOFF   ((size_t)3072)
#define SQOFF  (HOFF + (size_t)NP*Cc)
#define A1OFF  (SQOFF + (size_t)NP)
#define ADOFF  (A1OFF + (size_t)NP*F2)
#define HXOFF  (ADOFF + (size_t)NP*Cc)
#define IXOFF  (HXOFF + (size_t)NP*Cc)
#define CNTOFF (IXOFF + (size_t)NP*KK)
#define FBNOFF (CNTOFF + (size_t)NP)
#define FBQOFF (FBNOFF + (size_t)64)
// byte offsets for the u16 arrays
#define HIBYTES   ((FBQOFF + (size_t)NP) * 4)
#define W2TBYTES  (HIBYTES + (size_t)NP*HSTRIDE*2)     // bf16 W2^T  [128][64]
#define WX2TBYTES (W2TBYTES + (size_t)128*64*2)        // bf16 Wx2^T [128][128]
#define CANDBYTES (WX2TBYTES + (size_t)128*128*2)

typedef __attribute__((ext_vector_type(8))) short bf16x8;
typedef __attribute__((ext_vector_type(4))) float f32x4;

__device__ __forceinline__ unsigned short f2bf(float f) {
  unsigned u = __float_as_uint(f);
  unsigned r = (u + 0x7FFFu + ((u >> 16) & 1u)) >> 16;
  return (unsigned short)r;
}
__device__ __forceinline__ float lrelu(float v) {
  return (v > 0.f ? v : 0.2f*v) * SQ2;
}

// ---------------------------------------------------------------------------
// Kernel 1: per-batch FiLM vectors
__global__ __launch_bounds__(512) void k_pervec(const float* __restrict__ w,
    const float* __restrict__ Wg, const float* __restrict__ Wb,
    const float* __restrict__ Wls, const float* __restrict__ bls,
    float* __restrict__ ws) {
  __shared__ float red[3][4][Cc];
  const int b = blockIdx.x;
  const int c = threadIdx.x & 127, dc = threadIdx.x >> 7;
  const float* wr = w + b*WD;
  float ag = 0.f, ab = 0.f, al = 0.f;
  for (int d = dc*128; d < dc*128 + 128; ++d) {
    float wv = wr[d];
    ag = fmaf(wv, Wg[d*Cc + c], ag);
    ab = fmaf(wv, Wb[d*Cc + c], ab);
    al = fmaf(wv, Wls[d*Cc + c], al);
  }
  red[0][dc][c] = ag; red[1][dc][c] = ab; red[2][dc][c] = al;
  __syncthreads();
  if (dc == 0) {
    float sg = red[0][0][c] + red[0][1][c] + red[0][2][c] + red[0][3][c];
    float sb = red[1][0][c] + red[1][1][c] + red[1][2][c] + red[1][3][c];
    float sl = red[2][0][c] + red[2][1][c] + red[2][2][c] + red[2][3][c];
    ws[GOFF  + b*Cc + c] = 1.0f + sg;
    ws[BEOFF + b*Cc + c] = sb;
    ws[LSOFF + b*Cc + c] = sl + bls[c];
  }
}

// ---------------------------------------------------------------------------
// Kernel 1b: bf16-transposed weight copies for the MFMA MLP.
__global__ __launch_bounds__(256) void k_wprep(const float* __restrict__ W2,
    const float* __restrict__ Wx2, unsigned short* __restrict__ w2t,
    unsigned short* __restrict__ wx2t) {
  int idx = blockIdx.x*256 + threadIdx.x;
  if (idx < 128*64)  { int c = idx >> 6, j = idx & 63;  w2t[idx]  = f2bf(W2[j*FO + c]); }
  if (idx < 128*128) { int c = idx >> 7, j = idx & 127; wx2t[idx] = f2bf(Wx2[j*FO + c]); }
}

// ---------------------------------------------------------------------------
// Kernel 2: h = LN(x)*g + beta, sq = sum(h*h), hi = bf16(h); zero fb queue.
__global__ __launch_bounds__(64) void k_h(const float* __restrict__ x,
                                          float* __restrict__ ws,
                                          unsigned short* __restrict__ hi_g,
                                          int* __restrict__ fbn) {
  const int n = blockIdx.x;
  const int b = n >> 11;
  const int t = threadIdx.x;
  if (n == 0 && t == 0) fbn[0] = 0;
  const float* xr = x + (size_t)n*Cc;
  float x0 = xr[t], x1 = xr[t + 64];
  float s = x0 + x1, ss = x0*x0 + x1*x1;
  #pragma unroll
  for (int m = 1; m < 64; m <<= 1) {
    s  += __shfl_xor(s,  m, 64);
    ss += __shfl_xor(ss, m, 64);
  }
  float mu  = s * (1.0f/128.0f);
  float var = ss * (1.0f/128.0f) - mu*mu;
  float rs  = rsqrtf(var + 1e-5f);
  float h0 = (x0 - mu)*rs*ws[GOFF + b*Cc + t]      + ws[BEOFF + b*Cc + t];
  float h1 = (x1 - mu)*rs*ws[GOFF + b*Cc + t + 64] + ws[BEOFF + b*Cc + t + 64];
  float* hr = ws + HOFF + (size_t)n*Cc;
  hr[t] = h0; hr[t + 64] = h1;
  hi_g[(size_t)n*HSTRIDE + t]      = f2bf(h0);
  hi_g[(size_t)n*HSTRIDE + t + 64] = f2bf(h1);
  float q = h0*h0 + h1*h1;
  #pragma unroll
  for (int m = 1; m < 64; m <<= 1) q += __shfl_xor(q, m, 64);
  if (t == 0) ws[SQOFF + n] = q;
}

// ---------------------------------------------------------------------------
// Kernel 3: precompute A1 = h@W1, Ad = h@Wx1[128:], hxb = h@Wx1[:128]-Ad+bx1
__global__ __launch_bounds__(128) void k_pre(const float* __restrict__ W1,
    const float* __restrict__ Wx1, const float* __restrict__ bx1,
    float* __restrict__ ws) {
  __shared__ float hs[4][Cc];
  const int t = threadIdx.x;
  const size_t row0 = (size_t)blockIdx.x * 4;
  const float* h = ws + HOFF;
  #pragma unroll
  for (int r = 0; r < 4; ++r) hs[r][t] = h[(row0 + r)*Cc + t];
  __syncthreads();
  float ad[4] = {0,0,0,0}, ac[4] = {0,0,0,0};
  for (int cp = 0; cp < Cc; ++cp) {
    float whi = Wx1[cp*FO + t];
    float wlo = Wx1[(Cc + cp)*FO + t];
    #pragma unroll
    for (int r = 0; r < 4; ++r) {
      float hv = hs[r][cp];
      ac[r] = fmaf(hv, whi, ac[r]);
      ad[r] = fmaf(hv, wlo, ad[r]);
    }
  }
  float bx = bx1[t];
  #pragma unroll
  for (int r = 0; r < 4; ++r) {
    ws[ADOFF + (row0 + r)*Cc + t] = ad[r];
    ws[HXOFF + (row0 + r)*Cc + t] = ac[r] - ad[r] + bx;
  }
  const int j = t & 63, rp = t >> 6;
  float a0 = 0.f, a1 = 0.f;
  for (int cp = 0; cp < Cc; ++cp) {
    float wv = W1[cp*F2 + j];
    a0 = fmaf(hs[rp][cp],     wv, a0);
    a1 = fmaf(hs[rp + 2][cp], wv, a1);
  }
  ws[A1OFF + (row0 + rp)*F2 + j]     = a0;
  ws[A1OFF + (row0 + rp + 2)*F2 + j] = a1;
}

// ---------------------------------------------------------------------------
// Kernel 4: MFMA approx distances + tau-filter compaction. (unchanged)
__global__ __launch_bounds__(512, 4) void k_filter(float* __restrict__ ws,
    const unsigned short* __restrict__ hi_g, unsigned short* __restrict__ cand,
    int* __restrict__ cnt_g, int CAP) {
  __shared__ unsigned short hiA[32*HSTRIDE];
  __shared__ float smB[8704];
  __shared__ float sqA[32], sqB[128], tauS[32];
  __shared__ int cnt[32];
  unsigned short* hB = (unsigned short*)smB;
  float* dstage = smB;
  const int t = threadIdx.x;
  const int b  = blockIdx.x >> 6;
  const int i0 = (blockIdx.x & 63) << 5;
  const int wave = t >> 6, lane = t & 63;
  const int wi = wave & 1, wj = wave >> 1;
  const int l15 = lane & 15, l4 = lane >> 4;
  const float* __restrict__ sq = ws + SQOFF + (size_t)b*Nn;
  const unsigned short* __restrict__ hib = hi_g + (size_t)b*Nn*HSTRIDE;

  { int r = t >> 4, o = (t & 15) * 8;
    *(bf16x8*)&hiA[r*HSTRIDE + o] = *(const bf16x8*)&hib[(size_t)(i0 + r)*HSTRIDE + o];
  }
  if (t < 32) { sqA[t] = sq[i0 + t]; cnt[t] = 0; }

  float samp[4][8];

  for (int jt = 0; jt < 4; ++jt) {
    const int j0 = jt << 7;
    __syncthreads();
    { int r = t >> 2, o = (t & 3) * 32;
      #pragma unroll
      for (int q = 0; q < 4; ++q)
        *(bf16x8*)&hB[r*HSTRIDE + o + q*8] =
            *(const bf16x8*)&hib[(size_t)(j0 + r)*HSTRIDE + o + q*8];
    }
    if (t < 128) sqB[t] = sq[j0 + t];
    __syncthreads();
    f32x4 acc0 = {0,0,0,0}, acc1 = {0,0,0,0};
    #pragma unroll
    for (int kb = 0; kb < 4; ++kb) {
      const int cbase = kb*32 + l4*8;
      bf16x8 a  = *(const bf16x8*)&hiA[(16*wi + l15)*HSTRIDE + cbase];
      bf16x8 b0 = *(const bf16x8*)&hB [(32*wj      + l15)*HSTRIDE + cbase];
      bf16x8 b1 = *(const bf16x8*)&hB [(32*wj + 16 + l15)*HSTRIDE + cbase];
      acc0 = __builtin_amdgcn_mfma_f32_16x16x32_bf16(a, b0, acc0, 0, 0, 0);
      acc1 = __builtin_amdgcn_mfma_f32_16x16x32_bf16(a, b1, acc1, 0, 0, 0);
    }
    __syncthreads();
    #pragma unroll
    for (int jb = 0; jb < 2; ++jb) {
      const f32x4 a = jb ? acc1 : acc0;
      #pragma unroll
      for (int r = 0; r < 4; ++r) {
        int il = 16*wi + l4*4 + r;
        int jl = 32*wj + 16*jb + l15;
        dstage[il*132 + jl] = sqA[il] + sqB[jl] - 2.f*a[r];
      }
    }
    __syncthreads();
    #pragma unroll
    for (int r = 0; r < 4; ++r) {
      int row = wave*4 + r;
      samp[r][jt*2]     = dstage[row*132 + lane];
      samp[r][jt*2 + 1] = dstage[row*132 + 64 + lane];
    }
  }

  {
    float lo[4], hi[4];
    #pragma unroll
    for (int r = 0; r < 4; ++r) {
      float m = samp[r][0];
      #pragma unroll
      for (int k = 1; k < 8; ++k) m = fmaxf(m, samp[r][k]);
      #pragma unroll
      for (int s2 = 1; s2 < 64; s2 <<= 1) m = fmaxf(m, __shfl_xor(m, s2, 64));
      hi[r] = fmaxf(m, 0.f)*1.0001f + 1e-6f;
      lo[r] = 0.f;
    }
    #pragma unroll 1
    for (int it = 0; it < 18; ++it) {
      float mid[4], cv[4];
      #pragma unroll
      for (int r = 0; r < 4; ++r) {
        mid[r] = 0.5f*(lo[r] + hi[r]);
        float c = 0.f;
        #pragma unroll
        for (int k = 0; k < 8; ++k) c += (samp[r][k] < mid[r]) ? 1.f : 0.f;
        cv[r] = c;
      }
      #pragma unroll
      for (int s2 = 1; s2 < 64; s2 <<= 1) {
        #pragma unroll
        for (int r = 0; r < 4; ++r) cv[r] += __shfl_xor(cv[r], s2, 64);
      }
      #pragma unroll
      for (int r = 0; r < 4; ++r) {
        bool ge = cv[r] >= 20.f;
        hi[r] = ge ? mid[r] : hi[r];
        lo[r] = ge ? lo[r] : mid[r];
      }
    }
    if (lane == 0) {
      #pragma unroll
      for (int r = 0; r < 4; ++r) tauS[wave*4 + r] = hi[r];
    }
    __syncthreads();
    #pragma unroll
    for (int r = 0; r < 4; ++r) {
      int row = wave*4 + r;
      float tv = hi[r];
      size_t rg = (size_t)(b*Nn + i0 + row);
      #pragma unroll
      for (int k = 0; k < 8; ++k) {
        if (samp[r][k] < tv) {
          int j = (k >> 1)*128 + (k & 1)*64 + lane;
          int pos = atomicAdd(&cnt[row], 1);
          if (pos < CAP) cand[rg*CAPMAX + pos] = (unsigned short)j;
        }
      }
    }
  }

  for (int jt = 4; jt < 16; ++jt) {
    const int j0 = jt << 7;
    __syncthreads();
    { int r = t >> 2, o = (t & 3) * 32;
      #pragma unroll
      for (int q = 0; q < 4; ++q)
        *(bf16x8*)&hB[r*HSTRIDE + o + q*8] =
            *(const bf16x8*)&hib[(size_t)(j0 + r)*HSTRIDE + o + q*8];
    }
    if (t < 128) sqB[t] = sq[j0 + t];
    __syncthreads();
    f32x4 acc0 = {0,0,0,0}, acc1 = {0,0,0,0};
    #pragma unroll
    for (int kb = 0; kb < 4; ++kb) {
      const int cbase = kb*32 + l4*8;
      bf16x8 a  = *(const bf16x8*)&hiA[(16*wi + l15)*HSTRIDE + cbase];
      bf16x8 b0 = *(const bf16x8*)&hB [(32*wj      + l15)*HSTRIDE + cbase];
      bf16x8 b1 = *(const bf16x8*)&hB [(32*wj + 16 + l15)*HSTRIDE + cbase];
      acc0 = __builtin_amdgcn_mfma_f32_16x16x32_bf16(a, b0, acc0, 0, 0, 0);
      acc1 = __builtin_amdgcn_mfma_f32_16x16x32_bf16(a, b1, acc1, 0, 0, 0);
    }
    #pragma unroll
    for (int jb = 0; jb < 2; ++jb) {
      const f32x4 a = jb ? acc1 : acc0;
      #pragma unroll
      for (int r = 0; r < 4; ++r) {
        int il = 16*wi + l4*4 + r;
        int jl = 32*wj + 16*jb + l15;
        float dv = sqA[il] + sqB[jl] - 2.f*a[r];
        if (dv < tauS[il]) {
          int pos = atomicAdd(&cnt[il], 1);
          if (pos < CAP)
            cand[(size_t)(b*Nn + i0 + il)*CAPMAX + pos] = (unsigned short)(j0 + jl);
        }
      }
    }
  }
  __syncthreads();
  if (t < 32) cnt_g[b*Nn + i0 + t] = cnt[t];
}

// ---------------------------------------------------------------------------
// Kernel 5: exact fp32 refine + fb-queue append. XCD-swizzled. (unchanged)
__global__ __launch_bounds__(256) void k_refine(float* __restrict__ ws,
    const unsigned short* __restrict__ cand, const int* __restrict__ cnt_g,
    int* __restrict__ fbn, int* __restrict__ fbq, int CAP) {
  __shared__ float dsh[4][CAPMAX];
  __shared__ unsigned short cjs[4][CAPMAX];
  const int wave = threadIdx.x >> 6, lane = threadIdx.x & 63;
  const int s8 = lane >> 3, ch = lane & 7;
  const int blk = blockIdx.x;
  const int row = ((blk & 7)*512 + (blk >> 3))*4 + wave;
  const int b = row >> 11;
  const float* __restrict__ h = ws + HOFF;
  int c_ = cnt_g[row];
  int cm = (c_ < 17 || c_ > CAP) ? 0 : c_;
  if (cm == 0 && lane == 0) { int q = atomicAdd(fbn, 1); fbq[q] = row; }
  for (int cc = lane; cc < cm; cc += 64)
    cjs[wave][cc] = cand[(size_t)row*CAPMAX + cc];
  float4 hi4[4];
  #pragma unroll
  for (int q = 0; q < 4; ++q)
    hi4[q] = *(const float4*)&h[(size_t)row*Cc + ch*4 + q*32];
  __syncthreads();
  const int np8 = (cm + 7) >> 3;
  for (int p = 0; p < np8; ++p) {
    int slot = p*8 + s8;
    int sl = slot < cm ? slot : 0;
    int jj = cjs[wave][sl];
    const float* hj = h + (size_t)(b*Nn + jj)*Cc;
    float part = 0.f;
    #pragma unroll
    for (int q = 0; q < 4; ++q) {
      float4 v = *(const float4*)&hj[ch*4 + q*32];
      float e0 = hi4[q].x - v.x, e1 = hi4[q].y - v.y;
      float e2 = hi4[q].z - v.z, e3 = hi4[q].w - v.w;
      part = fmaf(e0, e0, part); part = fmaf(e1, e1, part);
      part = fmaf(e2, e2, part); part = fmaf(e3, e3, part);
    }
    part += __shfl_xor(part, 1, 64);
    part += __shfl_xor(part, 2, 64);
    part += __shfl_xor(part, 4, 64);
    if (ch == 0 && slot < cm) dsh[wave][slot] = part;
  }
  __syncthreads();
  int* op = (int*)(ws + IXOFF) + (size_t)row*KK;
  for (int cc = lane; cc < cm; cc += 64) {
    float dc = dsh[wave][cc];
    int jc = cjs[wave][cc];
    int rank = 0;
    #pragma unroll 1
    for (int m = 0; m < cm; ++m) {
      float dm = dsh[wave][m];
      int jm = cjs[wave][m];
      rank += (dm < dc || (dm == dc && jm < jc)) ? 1 : 0;
    }
    if (rank >= 1 && rank <= 16) op[rank - 1] = b*Nn + jc;
  }
}

// ---------------------------------------------------------------------------
// Kernel 6: fallback — queue-driven (expected empty). (unchanged)
__global__ __launch_bounds__(256) void k_fb(float* __restrict__ ws,
    const int* __restrict__ fbn, const int* __restrict__ fbq) {
  __shared__ float fd[4][17];
  __shared__ int   fj[4][17];
  __shared__ float his[128];
  const int wave = threadIdx.x >> 6, lane = threadIdx.x & 63;
  int nfb = fbn[0];
  nfb = (nfb < 0) ? 0 : ((nfb > NP) ? NP : nfb);
  for (int q = blockIdx.x; q < nfb; q += gridDim.x) {
    const int row = fbq[q];
    if ((unsigned)row >= (unsigned)NP) continue;
    const int b = row >> 11;
    const float* __restrict__ h = ws + HOFF + (size_t)b*Nn*Cc;
    if (threadIdx.x < 128) his[threadIdx.x] = h[(size_t)(row & (Nn-1))*Cc + threadIdx.x];
    __syncthreads();
    const float hi0 = his[lane], hi1 = his[lane + 64];
    float td[17]; int tj[17];
    #pragma unroll
    for (int s = 0; s < 17; ++s) { td[s] = 3.0e38f; tj[s] = 0x7FFFFFFF; }
    float cmax = 3.0e38f; int cjm = 0x7FFFFFFF, cpos = 0;
    const int jb = wave*512;
    #pragma unroll 1
    for (int it = 0; it < 256; ++it) {
      int j = jb + it*2;
      float a0 = h[(size_t)j*Cc + lane],     a1 = h[(size_t)j*Cc + lane + 64];
      float b0 = h[(size_t)(j+1)*Cc + lane], b1 = h[(size_t)(j+1)*Cc + lane + 64];
      float e0 = hi0 - a0, e1 = hi1 - a1, f0 = hi0 - b0, f1 = hi1 - b1;
      float p0 = e0*e0; p0 = fmaf(e1, e1, p0);
      float p1 = f0*f0; p1 = fmaf(f1, f1, p1);
      #pragma unroll
      for (int s2 = 1; s2 < 64; s2 <<= 1) {
        p0 += __shfl_xor(p0, s2, 64);
        p1 += __shfl_xor(p1, s2, 64);
      }
      #pragma unroll
      for (int u = 0; u < 2; ++u) {
        float d = u ? p1 : p0;
        int jd = j + u;
        if (d < cmax || (d == cmax && jd < cjm)) {
          #pragma unroll
          for (int s = 0; s < 17; ++s) {
            bool r = (s == cpos);
            td[s] = r ? d  : td[s];
            tj[s] = r ? jd : tj[s];
          }
          cmax = td[0]; cjm = tj[0]; cpos = 0;
          #pragma unroll
          for (int s = 1; s < 17; ++s)
            if (td[s] > cmax || (td[s] == cmax && tj[s] > cjm)) {
              cmax = td[s]; cjm = tj[s]; cpos = s;
            }
        }
      }
    }
    if (lane == 0) {
      #pragma unroll
      for (int s = 0; s < 17; ++s) { fd[wave][s] = td[s]; fj[wave][s] = tj[s]; }
    }
    __syncthreads();
    if (threadIdx.x < 68) {
      int e = threadIdx.x;
      float dc = fd[e / 17][e % 17];
      int   jc = fj[e / 17][e % 17];
      int rank = 0;
      #pragma unroll 1
      for (int m = 0; m < 68; ++m) {
        float dm = fd[m / 17][m % 17];
        int jm = fj[m / 17][m % 17];
        rank += (dm < dc || (dm == dc && jm < jc)) ? 1 : 0;
      }
      if (rank >= 1 && rank <= 16) {
        int* op = (int*)(ws + IXOFF) + (size_t)row*KK;
        op[rank - 1] = b*Nn + jc;
      }
    }
    __syncthreads();
  }
}

// ---------------------------------------------------------------------------
// Kernel 7: MFMA per-point MLP, weights staged in LDS (+16B row pad so each
// b128 fragment read distributes 8 lanes per 4-bank group = the inherent
// floor). 32 points/block (8/wave) amortize the 52KB staging; b1/bx2/ls
// hoisted out of the point loop. XCD swizzle kept (blk&7 = batch).
#define W2S_STRIDE  72    // shorts per row (64 + 8): 144B, 16B-aligned
#define WX2S_STRIDE 136   // shorts per row (128 + 8): 272B, 16B-aligned
__global__ __launch_bounds__(256) void k_mlp(
    const float* __restrict__ b1v, const float* __restrict__ bx2,
    const unsigned short* __restrict__ w2t, const unsigned short* __restrict__ wx2t,
    const float* __restrict__ x, float* __restrict__ out,
    float* __restrict__ ws) {
  __shared__ unsigned short w2s[128*W2S_STRIDE];     // 18432 B
  __shared__ unsigned short wx2s[128*WX2S_STRIDE];   // 34816 B
  const int wave = threadIdx.x >> 6, lane = threadIdx.x & 63;
  const int l15 = lane & 15, l4 = lane >> 4;
  const int blk = blockIdx.x;
  const int bb = blk & 7;                         // batch (XCD-local)
  const int nbase = bb*Nn + (blk >> 3)*32 + wave*8;

  // stage weights into padded LDS (coalesced global reads)
  for (int i = threadIdx.x*8; i < 128*64; i += 256*8) {
    int j = i >> 6, k = i & 63;
    *(bf16x8*)&w2s[j*W2S_STRIDE + k] = *(const bf16x8*)&w2t[i];
  }
  for (int i = threadIdx.x*8; i < 128*128; i += 256*8) {
    int j = i >> 7, k = i & 127;
    *(bf16x8*)&wx2s[j*WX2S_STRIDE + k] = *(const bf16x8*)&wx2t[i];
  }

  // hoist wave-invariant vectors
  float4 b1f[4];
  #pragma unroll
  for (int c = 0; c < 2; ++c) {
    b1f[c*2]     = *(const float4*)(b1v + c*32 + l4*8);
    b1f[c*2 + 1] = *(const float4*)(b1v + c*32 + l4*8 + 4);
  }
  float bxv[8], lsv[8];
  #pragma unroll
  for (int nt = 0; nt < 8; ++nt) {
    bxv[nt] = bx2[nt*16 + l15];
    lsv[nt] = ws[LSOFF + bb*Cc + nt*16 + l15];
  }
  __syncthreads();

  const int* __restrict__ ipg = (const int*)(ws + IXOFF);
  const float* __restrict__ A1 = ws + A1OFF;
  int mk = ipg[(size_t)nbase*KK + l15];           // first point's gather index

  #pragma unroll 1
  for (int p = 0; p < 8; ++p) {
    const int n = nbase + p;
    int mk_next = (p < 7) ? ipg[(size_t)(n + 1)*KK + l15] : 0;

    // --- gather phase ---
    const float* a1m = A1 + (size_t)mk*F2;
    const float* a1n = A1 + (size_t)n*F2;
    bf16x8 hwA[2];
    #pragma unroll
    for (int c = 0; c < 2; ++c) {
      int off = c*32 + l4*8;
      float4 p0 = *(const float4*)(a1m + off), p1 = *(const float4*)(a1m + off + 4);
      float4 q0 = *(const float4*)(a1n + off), q1 = *(const float4*)(a1n + off + 4);
      float4 b0 = b1f[c*2], b1_ = b1f[c*2 + 1];
      bf16x8 r;
      r[0] = (short)f2bf(lrelu(p0.x - q0.x + b0.x));
      r[1] = (short)f2bf(lrelu(p0.y - q0.y + b0.y));
      r[2] = (short)f2bf(lrelu(p0.z - q0.z + b0.z));
      r[3] = (short)f2bf(lrelu(p0.w - q0.w + b0.w));
      r[4] = (short)f2bf(lrelu(p1.x - q1.x + b1_.x));
      r[5] = (short)f2bf(lrelu(p1.y - q1.y + b1_.y));
      r[6] = (short)f2bf(lrelu(p1.z - q1.z + b1_.z));
      r[7] = (short)f2bf(lrelu(p1.w - q1.w + b1_.w));
      hwA[c] = r;
    }
    const float* adm = ws + ADOFF + (size_t)mk*Cc;
    const float* hxb = ws + HXOFF + (size_t)n*Cc;
    bf16x8 hxA[4];
    #pragma unroll
    for (int c = 0; c < 4; ++c) {
      int off = c*32 + l4*8;
      float4 p0 = *(const float4*)(adm + off), p1 = *(const float4*)(adm + off + 4);
      float4 q0 = *(const float4*)(hxb + off), q1 = *(const float4*)(hxb + off + 4);
      bf16x8 r;
      r[0] = (short)f2bf(lrelu(p0.x + q0.x));
      r[1] = (short)f2bf(lrelu(p0.y + q0.y));
      r[2] = (short)f2bf(lrelu(p0.z + q0.z));
      r[3] = (short)f2bf(lrelu(p0.w + q0.w));
      r[4] = (short)f2bf(lrelu(p1.x + q1.x));
      r[5] = (short)f2bf(lrelu(p1.y + q1.y));
      r[6] = (short)f2bf(lrelu(p1.z + q1.z));
      r[7] = (short)f2bf(lrelu(p1.w + q1.w));
      hxA[c] = r;
    }

    // --- wlog = hw @ W2 -> softmax over k-slots ---
    f32x4 wl[8];
    #pragma unroll
    for (int nt = 0; nt < 8; ++nt) {
      f32x4 acc = {0,0,0,0};
      acc = __builtin_amdgcn_mfma_f32_16x16x32_bf16(hwA[0],
              *(const bf16x8*)&w2s[(nt*16 + l15)*W2S_STRIDE + l4*8], acc, 0, 0, 0);
      acc = __builtin_amdgcn_mfma_f32_16x16x32_bf16(hwA[1],
              *(const bf16x8*)&w2s[(nt*16 + l15)*W2S_STRIDE + 32 + l4*8], acc, 0, 0, 0);
      wl[nt] = acc;
    }
    #pragma unroll
    for (int nt = 0; nt < 8; ++nt) {
      float mx = fmaxf(fmaxf(wl[nt][0], wl[nt][1]), fmaxf(wl[nt][2], wl[nt][3]));
      mx = fmaxf(mx, __shfl_xor(mx, 16, 64));
      mx = fmaxf(mx, __shfl_xor(mx, 32, 64));
      float e0 = __expf(wl[nt][0] - mx), e1 = __expf(wl[nt][1] - mx);
      float e2 = __expf(wl[nt][2] - mx), e3 = __expf(wl[nt][3] - mx);
      float sm = e0 + e1 + e2 + e3;
      sm += __shfl_xor(sm, 16, 64);
      sm += __shfl_xor(sm, 32, 64);
      float rs = 1.0f / sm;
      wl[nt][0] = e0*rs; wl[nt][1] = e1*rs; wl[nt][2] = e2*rs; wl[nt][3] = e3*rs;
    }

    // --- xe = hx @ Wx2; agg; out = agg*ls + x ---
    #pragma unroll
    for (int nt = 0; nt < 8; ++nt) {
      f32x4 acc = {0,0,0,0};
      #pragma unroll
      for (int c = 0; c < 4; ++c)
        acc = __builtin_amdgcn_mfma_f32_16x16x32_bf16(hxA[c],
                *(const bf16x8*)&wx2s[(nt*16 + l15)*WX2S_STRIDE + c*32 + l4*8],
                acc, 0, 0, 0);
      float bx = bxv[nt];
      float ap = wl[nt][0]*(acc[0] + bx) + wl[nt][1]*(acc[1] + bx)
               + wl[nt][2]*(acc[2] + bx) + wl[nt][3]*(acc[3] + bx);
      ap += __shfl_xor(ap, 16, 64);
      ap += __shfl_xor(ap, 32, 64);
      if (l4 == 0) {
        size_t xo = (size_t)n*Cc + nt*16 + l15;
        out[xo] = fmaf(ap, lsv[nt], x[xo]);
      }
    }
    mk = mk_next;
  }
}

// ---------------------------------------------------------------------------
extern "C" void kernel_launch(void* const* d_in, const int* in_sizes, int n_in,
                              void* d_out, int out_size, void* d_ws, size_t ws_size,
                              hipStream_t stream) {
  const float* x   = (const float*)d_in[0];
  const float* w   = (const float*)d_in[1];
  const float* Wg  = (const float*)d_in[2];
  const float* Wb  = (const float*)d_in[3];
  const float* W1  = (const float*)d_in[4];
  const float* b1  = (const float*)d_in[5];
  const float* W2  = (const float*)d_in[6];
  const float* Wx1 = (const float*)d_in[8];
  const float* bx1 = (const float*)d_in[9];
  const float* Wx2 = (const float*)d_in[10];
  const float* bx2 = (const float*)d_in[11];
  const float* Wls = (const float*)d_in[12];
  const float* bls = (const float*)d_in[13];
  float* out = (float*)d_out;
  float* ws  = (float*)d_ws;
  unsigned short* hi_g = (unsigned short*)((char*)d_ws + HIBYTES);
  unsigned short* w2t  = (unsigned short*)((char*)d_ws + W2TBYTES);
  unsigned short* wx2t = (unsigned short*)((char*)d_ws + WX2TBYTES);
  unsigned short* cand = (unsigned short*)((char*)d_ws + CANDBYTES);
  int* cnt_g = (int*)(ws + CNTOFF);
  int* fbn   = (int*)(ws + FBNOFF);
  int* fbq   = (int*)(ws + FBQOFF);

  int CAP = 0;
  if (ws_size > CANDBYTES) {
    size_t c = (ws_size - CANDBYTES) / ((size_t)NP * 2);
    CAP = (c >= CAPMAX) ? CAPMAX : (int)c;
  }

  k_pervec<<<Bz, 512, 0, stream>>>(w, Wg, Wb, Wls, bls, ws);
  k_wprep<<<64, 256, 0, stream>>>(W2, Wx2, w2t, wx2t);
  k_h<<<NP, 64, 0, stream>>>(x, ws, hi_g, fbn);
  k_pre<<<NP/4, 128, 0, stream>>>(W1, Wx1, bx1, ws);
  k_filter<<<512, 512, 0, stream>>>(ws, hi_g, cand, cnt_g, CAP);
  k_refine<<<NP/4, 256, 0, stream>>>(ws, cand, cnt_g, fbn, fbq, CAP);
  k_fb<<<256, 256, 0, stream>>>(ws, fbn, fbq);
  k_mlp<<<512, 256, 0, stream>>>(b1, bx2, w2t, wx2t, x, out, ws);
}